// Round 13
// baseline (188.637 us; speedup 1.0000x reference)
//
#include <hip/hip_runtime.h>
#include <hip/hip_bf16.h>

#define NEG_SLOPE 0.2f
#define BN_EPS 1e-5f

typedef _Float16 half8 __attribute__((ext_vector_type(8)));
typedef _Float16 half2v __attribute__((ext_vector_type(2)));
typedef float f32x4 __attribute__((ext_vector_type(4)));

// ---------- fast zero of scratch (replaces pathological runtime fill) ----------
__global__ void k_zero(uint4* __restrict__ p, int n4) {
    int i = blockIdx.x * blockDim.x + threadIdx.x;
    if (i < n4) p[i] = (uint4){0u, 0u, 0u, 0u};
}

// ---------- setup: coef (blk0), gbounds (blk1), w2t transpose (blk2..129),
//            zero out (blk130..137), edge degree count (blk138..) ----------
__global__ void k_setup(const float* __restrict__ W1, const float* __restrict__ asw,
                        const float* __restrict__ adw, float* __restrict__ coef,
                        const float* __restrict__ W2, _Float16* __restrict__ w2t,
                        const int* __restrict__ batch, int N, int G, int* __restrict__ gb,
                        const int* __restrict__ ei, int E, int E2, int* __restrict__ cnt,
                        float* __restrict__ outp, int outN) {
    int bid = blockIdx.x, t = threadIdx.x;
    if (bid == 0) {
        float w0 = W1[t], w1 = W1[256 + t], as = asw[t], ad = adw[t];
        float v0 = w0 * as, v1 = w1 * as, v2 = w0 * ad, v3 = w1 * ad;
        for (int o = 32; o; o >>= 1) {
            v0 += __shfl_down(v0, o); v1 += __shfl_down(v1, o);
            v2 += __shfl_down(v2, o); v3 += __shfl_down(v3, o);
        }
        if ((t & 63) == 0) {
            int h = t >> 6;
            coef[h * 4 + 0] = v0; coef[h * 4 + 1] = v1;
            coef[h * 4 + 2] = v2; coef[h * 4 + 3] = v3;
        }
    } else if (bid == 1) {
        int g = t;
        if (g <= G) {
            int lo = 0, hi = N;
            while (lo < hi) { int mid = (lo + hi) >> 1; if (batch[mid] < g) lo = mid + 1; else hi = mid; }
            gb[g] = lo;
        }
    } else if (bid < 130) {
        int c = bid - 2;                     // 0..127
        w2t[(size_t)c * 256 + t] = (_Float16)W2[(size_t)t * 128 + c];
    } else if (bid < 138) {
        for (int i = (bid - 130) * 2048 + t; i < outN; i += 8 * 2048) outp[i] = 0.f;
    } else {
        int i = (bid - 138) * 256 + t;
        if (i < E2) {
            int d = (i < E) ? ei[E + i] : (i - E);
            atomicAdd(&cnt[d], 1);
        }
    }
}

// ---------- hierarchical scan, stage 1: block-local exclusive scan + block sums ----------
__global__ void k_scan1(const int* __restrict__ cnt, int* __restrict__ rp,
                        int* __restrict__ bsums, int n) {
    __shared__ int s[1024];
    int i = blockIdx.x * 1024 + threadIdx.x;
    int v = (i < n) ? cnt[i] : 0;
    s[threadIdx.x] = v;
    __syncthreads();
    for (int o = 1; o < 1024; o <<= 1) {
        int t = (threadIdx.x >= o) ? s[threadIdx.x - o] : 0;
        __syncthreads();
        s[threadIdx.x] += t;
        __syncthreads();
    }
    if (i < n) rp[i] = s[threadIdx.x] - v;
    if (threadIdx.x == 1023) bsums[blockIdx.x] = s[1023];
}

// ---------- stage 2: per-block redundant prefix of bsums + offset add ----------
__global__ void k_scan2f(int* __restrict__ rp, const int* __restrict__ bsums,
                         int n, int total) {
    __shared__ int boff;
    if (threadIdx.x == 0) {
        int run = 0;
        for (int b = 0; b < (int)blockIdx.x; b++) run += bsums[b];
        boff = run;
    }
    __syncthreads();
    int i = blockIdx.x * 1024 + threadIdx.x;
    if (i < n) rp[i] += boff;
    if (blockIdx.x == 0 && threadIdx.x == 0) rp[n] = total;
}

__global__ void k_scatter(const int* __restrict__ ei, int E, int E2,
                          const int* __restrict__ rp, int* __restrict__ cur,
                          int* __restrict__ esrc) {
    int i = blockIdx.x * blockDim.x + threadIdx.x;
    if (i >= E2) return;
    int s, d;
    if (i < E) { s = ei[i]; d = ei[E + i]; } else { s = d = i - E; }
    int pos = rp[d] + atomicAdd(&cur[d], 1);
    esrc[pos] = s;
}

// ---------- Layer 1 aggregation (rank-2) + fused BN1 stats reduction ----------
__global__ void k_agg1r(const int* __restrict__ rp, const int* __restrict__ esrc,
                        const float* __restrict__ x, const float* __restrict__ coef,
                        float* __restrict__ uv, float* __restrict__ stats, int N) {
    __shared__ float sred[4][20];
    int tid = threadIdx.x, lane = tid & 63, wid = tid >> 6;
    int n = blockIdx.x * blockDim.x + tid;
    float st[20];
    #pragma unroll
    for (int i = 0; i < 20; i++) st[i] = 0.f;

    if (n < N) {
        float c[16];
        #pragma unroll
        for (int i = 0; i < 16; i++) c[i] = coef[i];
        float2 xn = ((const float2*)x)[n];
        float ad[4], den[4], sx[4], sy[4];
        #pragma unroll
        for (int h = 0; h < 4; h++) {
            ad[h] = fmaf(xn.x, c[h * 4 + 2], xn.y * c[h * 4 + 3]);
            den[h] = 0.f; sx[h] = 0.f; sy[h] = 0.f;
        }
        int beg = rp[n], end = rp[n + 1];
        for (int k = beg; k < end; k++) {
            int s = esrc[k];
            float2 xv = ((const float2*)x)[s];
            #pragma unroll
            for (int h = 0; h < 4; h++) {
                float e = fmaf(xv.x, c[h * 4 + 0], xv.y * c[h * 4 + 1]) + ad[h];
                e = e > 0.f ? e : NEG_SLOPE * e;
                float w = __expf(e);
                den[h] += w; sx[h] = fmaf(w, xv.x, sx[h]); sy[h] = fmaf(w, xv.y, sy[h]);
            }
        }
        float* o = uv + (size_t)n * 8;
        #pragma unroll
        for (int h = 0; h < 4; h++) {
            float inv = 1.f / (den[h] + 1e-16f);
            float u = sx[h] * inv, v = sy[h] * inv;
            o[h] = u; o[4 + h] = v;
            st[h] = u; st[4 + h] = v;
            st[8 + h] = u * u; st[12 + h] = v * v; st[16 + h] = u * v;
        }
    }
    #pragma unroll
    for (int i = 0; i < 20; i++)
        for (int o = 32; o; o >>= 1) st[i] += __shfl_down(st[i], o);
    if (lane == 0)
        #pragma unroll
        for (int i = 0; i < 20; i++) sred[wid][i] = st[i];
    __syncthreads();
    if (tid < 20)
        atomicAdd(&stats[tid], sred[0][tid] + sred[1][tid] + sred[2][tid] + sred[3][tid]);
}

// ---------- fold BN1(analytic)+bias+W1 into per-column affine A0,A1,A2 ----------
__global__ void k_bn1coef(const float* __restrict__ stats, const float* __restrict__ W1,
                          const float* __restrict__ b1, const float* __restrict__ gamma,
                          const float* __restrict__ beta, float* __restrict__ abc, int N) {
    int j = threadIdx.x;  // 256
    int h = j >> 6;
    float w0 = W1[j], w1 = W1[256 + j], b = b1[j];
    float Su = stats[h], Sv = stats[4 + h], Suu = stats[8 + h], Svv = stats[12 + h], Suv = stats[16 + h];
    float fN = (float)N;
    float lin = fmaf(w0, Su, w1 * Sv);
    float mean = lin / fN + b;
    float sq = w0 * w0 * Suu + w1 * w1 * Svv + 2.f * w0 * w1 * Suv + 2.f * b * lin + fN * b * b;
    float var = sq / fN - mean * mean;
    float sc = rsqrtf(var + BN_EPS) * gamma[j];
    float sh = beta[j] - mean * sc;
    abc[j] = sc * w0;
    abc[256 + j] = sc * w1;
    abc[512 + j] = fmaf(sc, b, sh);
}

// ---------- Layer 2 GEMM via MFMA; B staged in LDS (2 x 32KB stages) ----------
__global__ __launch_bounds__(256) void k_gemm2(
        const float* __restrict__ uv, const float* __restrict__ abc,
        const _Float16* __restrict__ w2t,
        const float* __restrict__ asw, const float* __restrict__ adw,
        _Float16* __restrict__ g2h, float* __restrict__ as2,
        float* __restrict__ ad2, int N) {
    __shared__ _Float16 bs[128][136];
    int tid = threadIdx.x, wid = tid >> 6, l = tid & 63;
    int kg = l >> 4, ln = l & 15;
    int n0w = blockIdx.x * 64 + wid * 16;

    int arow = n0w + ln;
    float uvr[8];
    if (arow < N) {
        const float4* p = (const float4*)(uv + (size_t)arow * 8);
        float4 t0 = p[0], t1 = p[1];
        uvr[0] = t0.x; uvr[1] = t0.y; uvr[2] = t0.z; uvr[3] = t0.w;
        uvr[4] = t1.x; uvr[5] = t1.y; uvr[6] = t1.z; uvr[7] = t1.w;
    } else {
        #pragma unroll
        for (int i = 0; i < 8; i++) uvr[i] = 0.f;
    }

    f32x4 acc[8];
    #pragma unroll
    for (int ct = 0; ct < 8; ct++) acc[ct] = (f32x4){0.f, 0.f, 0.f, 0.f};

    int sc_ = tid >> 1, shalf = tid & 1;
    for (int s = 0; s < 2; s++) {
        #pragma unroll
        for (int j = 0; j < 8; j++) {
            *(half8*)&bs[sc_][shalf * 64 + j * 8] =
                *(const half8*)&w2t[(size_t)sc_ * 256 + s * 128 + shalf * 64 + j * 8];
        }
        __syncthreads();
        #pragma unroll
        for (int kt4 = 0; kt4 < 4; kt4++) {
            int kt = s * 4 + kt4;
            int h = kt >> 1;
            float u = uvr[h], v = uvr[4 + h];
            int kb = kt * 32 + kg * 8;
            float4 A0a = *(const float4*)&abc[kb],       A0b = *(const float4*)&abc[kb + 4];
            float4 A1a = *(const float4*)&abc[256 + kb], A1b = *(const float4*)&abc[256 + kb + 4];
            float4 A2a = *(const float4*)&abc[512 + kb], A2b = *(const float4*)&abc[512 + kb + 4];
            half8 af;
            float y;
            y = fmaf(A0a.x, u, fmaf(A1a.x, v, A2a.x)); af[0] = (_Float16)(y > 0.f ? y : __expf(y) - 1.f);
            y = fmaf(A0a.y, u, fmaf(A1a.y, v, A2a.y)); af[1] = (_Float16)(y > 0.f ? y : __expf(y) - 1.f);
            y = fmaf(A0a.z, u, fmaf(A1a.z, v, A2a.z)); af[2] = (_Float16)(y > 0.f ? y : __expf(y) - 1.f);
            y = fmaf(A0a.w, u, fmaf(A1a.w, v, A2a.w)); af[3] = (_Float16)(y > 0.f ? y : __expf(y) - 1.f);
            y = fmaf(A0b.x, u, fmaf(A1b.x, v, A2b.x)); af[4] = (_Float16)(y > 0.f ? y : __expf(y) - 1.f);
            y = fmaf(A0b.y, u, fmaf(A1b.y, v, A2b.y)); af[5] = (_Float16)(y > 0.f ? y : __expf(y) - 1.f);
            y = fmaf(A0b.z, u, fmaf(A1b.z, v, A2b.z)); af[6] = (_Float16)(y > 0.f ? y : __expf(y) - 1.f);
            y = fmaf(A0b.w, u, fmaf(A1b.w, v, A2b.w)); af[7] = (_Float16)(y > 0.f ? y : __expf(y) - 1.f);
            int klo = kt4 * 32 + kg * 8;
            #pragma unroll
            for (int ct = 0; ct < 8; ct++) {
                half8 bf = *(const half8*)&bs[ct * 16 + ln][klo];
                acc[ct] = __builtin_amdgcn_mfma_f32_16x16x32_f16(af, bf, acc[ct], 0, 0, 0);
            }
        }
        __syncthreads();
    }

    _Float16 (*tbuf)[16][136] = (_Float16 (*)[16][136])&bs[0][0];
    #pragma unroll
    for (int ct = 0; ct < 8; ct++)
        #pragma unroll
        for (int r = 0; r < 4; r++)
            tbuf[wid][kg * 4 + r][ct * 16 + ln] = (_Float16)acc[ct][r];
    __syncthreads();

    int rr = l >> 2, cq = l & 3;
    int node = n0w + rr;
    half8 hv[4];
    #pragma unroll
    for (int j = 0; j < 4; j++) hv[j] = *(const half8*)&tbuf[wid][rr][cq * 32 + j * 8];
    float ps = 0.f, pd = 0.f;
    #pragma unroll
    for (int j = 0; j < 4; j++) {
        int cb = cq * 32 + j * 8;
        float4 s0 = *(const float4*)&asw[cb], s1 = *(const float4*)&asw[cb + 4];
        float4 d0 = *(const float4*)&adw[cb], d1 = *(const float4*)&adw[cb + 4];
        ps = fmaf((float)hv[j][0], s0.x, ps); pd = fmaf((float)hv[j][0], d0.x, pd);
        ps = fmaf((float)hv[j][1], s0.y, ps); pd = fmaf((float)hv[j][1], d0.y, pd);
        ps = fmaf((float)hv[j][2], s0.z, ps); pd = fmaf((float)hv[j][2], d0.z, pd);
        ps = fmaf((float)hv[j][3], s0.w, ps); pd = fmaf((float)hv[j][3], d0.w, pd);
        ps = fmaf((float)hv[j][4], s1.x, ps); pd = fmaf((float)hv[j][4], d1.x, pd);
        ps = fmaf((float)hv[j][5], s1.y, ps); pd = fmaf((float)hv[j][5], d1.y, pd);
        ps = fmaf((float)hv[j][6], s1.z, ps); pd = fmaf((float)hv[j][6], d1.z, pd);
        ps = fmaf((float)hv[j][7], s1.w, ps); pd = fmaf((float)hv[j][7], d1.w, pd);
    }
    ps += __shfl_xor(ps, 1); ps += __shfl_xor(ps, 2);
    pd += __shfl_xor(pd, 1); pd += __shfl_xor(pd, 2);
    if (node < N) {
        #pragma unroll
        for (int j = 0; j < 4; j++)
            *(half8*)&g2h[(size_t)node * 128 + cq * 32 + j * 8] = hv[j];
        if (cq == 0) { as2[node] = ps; ad2[node] = pd; }
    }
}

// ---------- Layer 2 aggregation: wave per node (high-TLP form) ----------
__global__ void k_agg2(const int* __restrict__ rp, const int* __restrict__ esrc,
                       const float* __restrict__ as2, const float* __restrict__ ad2,
                       const _Float16* __restrict__ g2h, const float* __restrict__ b2,
                       float* __restrict__ out2, int N) {
    int wid = threadIdx.x >> 6, lane = threadIdx.x & 63;
    int n = blockIdx.x * 4 + wid;
    if (n >= N) return;
    int beg = rp[n], end = rp[n + 1];
    float ad = ad2[n];
    float ax = 0.f, ay = 0.f, den = 0.f;
    for (int t0 = beg; t0 < end; t0 += 64) {
        int k = t0 + lane;
        int sl = 0; float wl = 0.f;
        if (k < end) {
            sl = esrc[k];
            float e = as2[sl] + ad;
            e = e > 0.f ? e : NEG_SLOPE * e;
            wl = __expf(e);
        }
        int nt = min(64, end - t0);
        for (int k2 = 0; k2 < nt; k2++) {
            float w = __shfl(wl, k2);
            int s = __shfl(sl, k2);
            half2v gv = ((const half2v*)g2h)[(size_t)s * 64 + lane];
            den += w;
            ax = fmaf(w, (float)gv[0], ax);
            ay = fmaf(w, (float)gv[1], ay);
        }
    }
    float inv = 1.f / (den + 1e-16f);
    float2 bv = ((const float2*)b2)[lane];
    float2 ov = { ax * inv + bv.x, ay * inv + bv.y };
    ((float2*)out2)[(size_t)n * 64 + lane] = ov;
}

// ---------- BN2 stats (512-block streaming pass) ----------
__global__ void k_bnstats(const float* __restrict__ v, int N, int F,
                          float* __restrict__ sum, float* __restrict__ sq) {
    int j = threadIdx.x;
    int rows = (N + gridDim.x - 1) / gridDim.x;
    int r0 = blockIdx.x * rows, r1 = min(N, r0 + rows);
    float s = 0.f, q = 0.f;
    for (int r = r0; r < r1; r++) { float t = v[(size_t)r * F + j]; s += t; q = fmaf(t, t, q); }
    atomicAdd(&sum[j], s);
    atomicAdd(&sq[j], q);
}

// ---------- pooling: row-parallel partial sums (BN2+ELU fused) ----------
__global__ void k_poolpart(const float* __restrict__ v, const int* __restrict__ batch,
                           const float* __restrict__ bnsum, const float* __restrict__ bnsq,
                           const float* __restrict__ gamma, const float* __restrict__ beta,
                           float* __restrict__ out, int N, int rowsPerBlock) {
    int j = threadIdx.x;  // 128
    float mu = bnsum[j] / N;
    float var = bnsq[j] / N - mu * mu;
    float sc = rsqrtf(var + BN_EPS) * gamma[j];
    float sh = beta[j] - mu * sc;
    int r0 = blockIdx.x * rowsPerBlock;
    if (r0 >= N) return;
    int r1 = min(N, r0 + rowsPerBlock);
    int curg = batch[r0];
    float acc = 0.f;
    for (int r = r0; r < r1; r++) {
        int g = batch[r];
        if (g != curg) {
            atomicAdd(&out[(size_t)curg * 128 + j], acc);
            curg = g; acc = 0.f;
        }
        float y = fmaf(v[(size_t)r * 128 + j], sc, sh);
        acc += y > 0.f ? y : (__expf(y) - 1.0f);
    }
    atomicAdd(&out[(size_t)curg * 128 + j], acc);
}

__global__ void k_divg(float* __restrict__ out, const int* __restrict__ gb) {
    int g = blockIdx.x, j = threadIdx.x;  // 128
    out[(size_t)g * 128 + j] /= fmaxf((float)(gb[g + 1] - gb[g]), 1.0f);
}

extern "C" void kernel_launch(void* const* d_in, const int* in_sizes, int n_in,
                              void* d_out, int out_size, void* d_ws, size_t ws_size,
                              hipStream_t stream) {
    const float* x     = (const float*)d_in[0];
    const int*   ei    = (const int*)d_in[1];
    const int*   batch = (const int*)d_in[2];
    const float* W1    = (const float*)d_in[4];
    const float* asw1  = (const float*)d_in[5];
    const float* adw1  = (const float*)d_in[6];
    const float* b1    = (const float*)d_in[7];
    const float* gamma1= (const float*)d_in[8];
    const float* beta1 = (const float*)d_in[9];
    const float* W2    = (const float*)d_in[10];
    const float* asw2  = (const float*)d_in[11];
    const float* adw2  = (const float*)d_in[12];
    const float* b2    = (const float*)d_in[13];
    const float* gamma2= (const float*)d_in[14];
    const float* beta2 = (const float*)d_in[15];
    float* out = (float*)d_out;

    const int N  = in_sizes[2];
    const int E  = in_sizes[1] / 2;
    const int E2 = E + N;
    const int G  = out_size / 128;

    char* ws = (char*)d_ws;
    size_t off = 0;
    auto A = [&](size_t bytes) { size_t o = off; off += (bytes + 255) & ~(size_t)255; return o; };
    _Float16* g2h  = (_Float16*)(ws + A((size_t)N * 128 * 2));
    _Float16* w2t  = (_Float16*)(ws + A((size_t)128 * 256 * 2));
    float* out2  = (float*)(ws + A((size_t)N * 128 * 4));
    float* uv    = (float*)(ws + A((size_t)N * 8 * 4));
    float* as2   = (float*)(ws + A((size_t)N * 4));
    float* ad2   = (float*)(ws + A((size_t)N * 4));
    float* coef  = (float*)(ws + A(16 * 4));
    float* abc   = (float*)(ws + A(768 * 4));
    int*   gb    = (int*)(ws + A((size_t)(G + 1) * 4));
    int*   rp    = (int*)(ws + A((size_t)(N + 1) * 4));
    int*   esrc  = (int*)(ws + A((size_t)E2 * 4));
    int*   bsums = (int*)(ws + A((size_t)((N + 1023) / 1024) * 4));
    // contiguous zero-region: cnt[N] | cnt2[N] | stats[20] | bnsum[256] | bnsq[256]
    size_t zbytes = ((size_t)2 * N + 20 + 256 + 256) * 4;
    size_t zoff = A(zbytes);
    int*   cnt   = (int*)(ws + zoff);
    int*   cnt2  = cnt + N;
    float* stats = (float*)(cnt2 + N);
    float* bnsum = stats + 20;
    float* bnsq  = bnsum + 256;

    const int nb = (N + 1023) / 1024;

    // 1: zero scratch (custom kernel; runtime fill path is ~45us for this size)
    int n4 = (int)((zbytes + 15) / 16);   // safe: region padded to 256B
    k_zero<<<(n4 + 255) / 256, 256, 0, stream>>>((uint4*)(ws + zoff), n4);

    // 2: setup (coef + gbounds + w2t + zero-out + degree count)
    int degBlocks = (E2 + 255) / 256;
    k_setup<<<138 + degBlocks, 256, 0, stream>>>(W1, asw1, adw1, coef, W2, w2t,
                                                 batch, N, G, gb, ei, E, E2, cnt,
                                                 out, G * 128);

    // 3-4: hierarchical scan -> rp
    k_scan1<<<nb, 1024, 0, stream>>>(cnt, rp, bsums, N);
    k_scan2f<<<nb, 1024, 0, stream>>>(rp, bsums, N, E2);

    // 5: scatter edges into CSR
    k_scatter<<<degBlocks, 256, 0, stream>>>(ei, E, E2, rp, cnt2, esrc);

    // 6: layer-1 rank-2 aggregation + BN1 stats
    k_agg1r<<<(N + 255) / 256, 256, 0, stream>>>(rp, esrc, x, coef, uv, stats, N);

    // 7: fold BN1 into affine
    k_bn1coef<<<1, 256, 0, stream>>>(stats, W1, b1, gamma1, beta1, abc, N);

    // 8: layer-2 GEMM via MFMA
    k_gemm2<<<(N + 63) / 64, 256, 0, stream>>>(uv, abc, w2t, asw2, adw2, g2h, as2, ad2, N);

    // 9: layer-2 aggregation (wave per node, high TLP)
    k_agg2<<<(N + 3) / 4, 256, 0, stream>>>(rp, esrc, as2, ad2, g2h, b2, out2, N);

    // 10: BN2 stats
    k_bnstats<<<512, 128, 0, stream>>>(out2, N, 128, bnsum, bnsq);

    // 11: pooling with fused BN2+ELU
    const int rowsPB = 64;
    k_poolpart<<<(N + rowsPB - 1) / rowsPB, 128, 0, stream>>>(out2, batch, bnsum, bnsq,
                                                              gamma2, beta2, out, N, rowsPB);
    // 12: divide by graph size
    k_divg<<<G, 128, 0, stream>>>(out, gb);
}

// Round 15
// 180.504 us; speedup vs baseline: 1.0451x; 1.0451x over previous
//
#include <hip/hip_runtime.h>
#include <hip/hip_bf16.h>

#define NEG_SLOPE 0.2f
#define BN_EPS 1e-5f

typedef _Float16 half8 __attribute__((ext_vector_type(8)));
typedef _Float16 half2v __attribute__((ext_vector_type(2)));
typedef float f32x4 __attribute__((ext_vector_type(4)));

// ---------- fast zero of scratch + output (both ranges, every call) ----------
__global__ void k_zero(uint4* __restrict__ p, int n4, uint4* __restrict__ q, int m4) {
    int i = blockIdx.x * blockDim.x + threadIdx.x;
    if (i < n4) p[i] = (uint4){0u, 0u, 0u, 0u};
    else if (i < n4 + m4) q[i - n4] = (uint4){0u, 0u, 0u, 0u};
}

// ---------- setup: coef (blk0), gbounds (blk1), w2t transpose (blk2..129),
//            edge degree count (blk130..) ----------
__global__ void k_setup(const float* __restrict__ W1, const float* __restrict__ asw,
                        const float* __restrict__ adw, float* __restrict__ coef,
                        const float* __restrict__ W2, _Float16* __restrict__ w2t,
                        const int* __restrict__ batch, int N, int G, int* __restrict__ gb,
                        const int* __restrict__ ei, int E, int E2, int* __restrict__ cnt) {
    int bid = blockIdx.x, t = threadIdx.x;
    if (bid == 0) {
        float w0 = W1[t], w1 = W1[256 + t], as = asw[t], ad = adw[t];
        float v0 = w0 * as, v1 = w1 * as, v2 = w0 * ad, v3 = w1 * ad;
        for (int o = 32; o; o >>= 1) {
            v0 += __shfl_down(v0, o); v1 += __shfl_down(v1, o);
            v2 += __shfl_down(v2, o); v3 += __shfl_down(v3, o);
        }
        if ((t & 63) == 0) {
            int h = t >> 6;
            coef[h * 4 + 0] = v0; coef[h * 4 + 1] = v1;
            coef[h * 4 + 2] = v2; coef[h * 4 + 3] = v3;
        }
    } else if (bid == 1) {
        int g = t;
        if (g <= G) {
            int lo = 0, hi = N;
            while (lo < hi) { int mid = (lo + hi) >> 1; if (batch[mid] < g) lo = mid + 1; else hi = mid; }
            gb[g] = lo;
        }
    } else if (bid < 130) {
        int c = bid - 2;                     // 0..127
        w2t[(size_t)c * 256 + t] = (_Float16)W2[(size_t)t * 128 + c];
    } else {
        int i = (bid - 130) * 256 + t;
        if (i < E2) {
            int d = (i < E) ? ei[E + i] : (i - E);
            atomicAdd(&cnt[d], 1);
        }
    }
}

// ---------- hierarchical scan, stage 1: block-local exclusive scan + block sums ----------
__global__ void k_scan1(const int* __restrict__ cnt, int* __restrict__ rp,
                        int* __restrict__ bsums, int n) {
    __shared__ int s[1024];
    int i = blockIdx.x * 1024 + threadIdx.x;
    int v = (i < n) ? cnt[i] : 0;
    s[threadIdx.x] = v;
    __syncthreads();
    for (int o = 1; o < 1024; o <<= 1) {
        int t = (threadIdx.x >= o) ? s[threadIdx.x - o] : 0;
        __syncthreads();
        s[threadIdx.x] += t;
        __syncthreads();
    }
    if (i < n) rp[i] = s[threadIdx.x] - v;
    if (threadIdx.x == 1023) bsums[blockIdx.x] = s[1023];
}

// ---------- stage 2: wave-parallel prefix of bsums + offset add (nb <= 64) ----------
__global__ void k_scan2f(int* __restrict__ rp, const int* __restrict__ bsums,
                         int n, int total, int nb) {
    __shared__ int boff;
    if (threadIdx.x < 64) {
        int lane = threadIdx.x;
        int v = (lane < nb) ? bsums[lane] : 0;
        #pragma unroll
        for (int o = 1; o < 64; o <<= 1) {
            int t = __shfl_up(v, o);
            if (lane >= o) v += t;
        }
        int ex = __shfl_up(v, 1);
        if (lane == (int)blockIdx.x) boff = (blockIdx.x == 0) ? 0 : ex;
    }
    __syncthreads();
    int i = blockIdx.x * 1024 + threadIdx.x;
    if (i < n) rp[i] += boff;
    if (blockIdx.x == 0 && threadIdx.x == 0) rp[n] = total;
}

// ---------- scatter: consumes cnt (deg) via atomicSub ----------
__global__ void k_scatter(const int* __restrict__ ei, int E, int E2,
                          const int* __restrict__ rp, int* __restrict__ cnt,
                          int* __restrict__ esrc) {
    int i = blockIdx.x * blockDim.x + threadIdx.x;
    if (i >= E2) return;
    int s, d;
    if (i < E) { s = ei[i]; d = ei[E + i]; } else { s = d = i - E; }
    int old = atomicSub(&cnt[d], 1);
    esrc[rp[d] + old - 1] = s;
}

// ---------- Layer 1 aggregation (rank-2) + fused BN1 stats reduction ----------
__global__ void k_agg1r(const int* __restrict__ rp, const int* __restrict__ esrc,
                        const float* __restrict__ x, const float* __restrict__ coef,
                        float* __restrict__ uv, float* __restrict__ stats, int N) {
    __shared__ float sred[4][20];
    int tid = threadIdx.x, lane = tid & 63, wid = tid >> 6;
    int n = blockIdx.x * blockDim.x + tid;
    float st[20];
    #pragma unroll
    for (int i = 0; i < 20; i++) st[i] = 0.f;

    if (n < N) {
        float c[16];
        #pragma unroll
        for (int i = 0; i < 16; i++) c[i] = coef[i];
        float2 xn = ((const float2*)x)[n];
        float ad[4], den[4], sx[4], sy[4];
        #pragma unroll
        for (int h = 0; h < 4; h++) {
            ad[h] = fmaf(xn.x, c[h * 4 + 2], xn.y * c[h * 4 + 3]);
            den[h] = 0.f; sx[h] = 0.f; sy[h] = 0.f;
        }
        int beg = rp[n], end = rp[n + 1];
        for (int k = beg; k < end; k++) {
            int s = esrc[k];
            float2 xv = ((const float2*)x)[s];
            #pragma unroll
            for (int h = 0; h < 4; h++) {
                float e = fmaf(xv.x, c[h * 4 + 0], xv.y * c[h * 4 + 1]) + ad[h];
                e = e > 0.f ? e : NEG_SLOPE * e;
                float w = __expf(e);
                den[h] += w; sx[h] = fmaf(w, xv.x, sx[h]); sy[h] = fmaf(w, xv.y, sy[h]);
            }
        }
        float* o = uv + (size_t)n * 8;
        #pragma unroll
        for (int h = 0; h < 4; h++) {
            float inv = 1.f / (den[h] + 1e-16f);
            float u = sx[h] * inv, v = sy[h] * inv;
            o[h] = u; o[4 + h] = v;
            st[h] = u; st[4 + h] = v;
            st[8 + h] = u * u; st[12 + h] = v * v; st[16 + h] = u * v;
        }
    }
    #pragma unroll
    for (int i = 0; i < 20; i++)
        for (int o = 32; o; o >>= 1) st[i] += __shfl_down(st[i], o);
    if (lane == 0)
        #pragma unroll
        for (int i = 0; i < 20; i++) sred[wid][i] = st[i];
    __syncthreads();
    if (tid < 20)
        atomicAdd(&stats[tid], sred[0][tid] + sred[1][tid] + sred[2][tid] + sred[3][tid]);
}

// ---------- Layer 2 GEMM via MFMA; BN1-coef computed in-block; B staged in LDS ----------
__global__ __launch_bounds__(256) void k_gemm2(
        const float* __restrict__ uv, const float* __restrict__ stats,
        const float* __restrict__ W1, const float* __restrict__ b1,
        const float* __restrict__ gamma, const float* __restrict__ beta,
        const _Float16* __restrict__ w2t,
        const float* __restrict__ asw, const float* __restrict__ adw,
        _Float16* __restrict__ g2h, float* __restrict__ as2,
        float* __restrict__ ad2, int N) {
    __shared__ _Float16 bs[128][136];
    __shared__ float abcs[768];
    int tid = threadIdx.x, wid = tid >> 6, l = tid & 63;
    int kg = l >> 4, ln = l & 15;
    int n0w = blockIdx.x * 64 + wid * 16;

    {
        int j = tid, h = j >> 6;
        float w0 = W1[j], w1 = W1[256 + j], b = b1[j];
        float Su = stats[h], Sv = stats[4 + h], Suu = stats[8 + h],
              Svv = stats[12 + h], Suv = stats[16 + h];
        float fN = (float)N;
        float lin = fmaf(w0, Su, w1 * Sv);
        float mean = lin / fN + b;
        float sq = w0 * w0 * Suu + w1 * w1 * Svv + 2.f * w0 * w1 * Suv + 2.f * b * lin + fN * b * b;
        float var = sq / fN - mean * mean;
        float sc = rsqrtf(var + BN_EPS) * gamma[j];
        float sh = beta[j] - mean * sc;
        abcs[j] = sc * w0;
        abcs[256 + j] = sc * w1;
        abcs[512 + j] = fmaf(sc, b, sh);
    }

    int arow = n0w + ln;
    float uvr[8];
    if (arow < N) {
        const float4* p = (const float4*)(uv + (size_t)arow * 8);
        float4 t0 = p[0], t1 = p[1];
        uvr[0] = t0.x; uvr[1] = t0.y; uvr[2] = t0.z; uvr[3] = t0.w;
        uvr[4] = t1.x; uvr[5] = t1.y; uvr[6] = t1.z; uvr[7] = t1.w;
    } else {
        #pragma unroll
        for (int i = 0; i < 8; i++) uvr[i] = 0.f;
    }

    f32x4 acc[8];
    #pragma unroll
    for (int ct = 0; ct < 8; ct++) acc[ct] = (f32x4){0.f, 0.f, 0.f, 0.f};

    int sc_ = tid >> 1, shalf = tid & 1;
    for (int s = 0; s < 2; s++) {
        #pragma unroll
        for (int j = 0; j < 8; j++) {
            *(half8*)&bs[sc_][shalf * 64 + j * 8] =
                *(const half8*)&w2t[(size_t)sc_ * 256 + s * 128 + shalf * 64 + j * 8];
        }
        __syncthreads();
        #pragma unroll
        for (int kt4 = 0; kt4 < 4; kt4++) {
            int kt = s * 4 + kt4;
            int h = kt >> 1;
            float u = uvr[h], v = uvr[4 + h];
            int kb = kt * 32 + kg * 8;
            float4 A0a = *(const float4*)&abcs[kb],       A0b = *(const float4*)&abcs[kb + 4];
            float4 A1a = *(const float4*)&abcs[256 + kb], A1b = *(const float4*)&abcs[256 + kb + 4];
            float4 A2a = *(const float4*)&abcs[512 + kb], A2b = *(const float4*)&abcs[512 + kb + 4];
            half8 af;
            float y;
            y = fmaf(A0a.x, u, fmaf(A1a.x, v, A2a.x)); af[0] = (_Float16)(y > 0.f ? y : __expf(y) - 1.f);
            y = fmaf(A0a.y, u, fmaf(A1a.y, v, A2a.y)); af[1] = (_Float16)(y > 0.f ? y : __expf(y) - 1.f);
            y = fmaf(A0a.z, u, fmaf(A1a.z, v, A2a.z)); af[2] = (_Float16)(y > 0.f ? y : __expf(y) - 1.f);
            y = fmaf(A0a.w, u, fmaf(A1a.w, v, A2a.w)); af[3] = (_Float16)(y > 0.f ? y : __expf(y) - 1.f);
            y = fmaf(A0b.x, u, fmaf(A1b.x, v, A2b.x)); af[4] = (_Float16)(y > 0.f ? y : __expf(y) - 1.f);
            y = fmaf(A0b.y, u, fmaf(A1b.y, v, A2b.y)); af[5] = (_Float16)(y > 0.f ? y : __expf(y) - 1.f);
            y = fmaf(A0b.z, u, fmaf(A1b.z, v, A2b.z)); af[6] = (_Float16)(y > 0.f ? y : __expf(y) - 1.f);
            y = fmaf(A0b.w, u, fmaf(A1b.w, v, A2b.w)); af[7] = (_Float16)(y > 0.f ? y : __expf(y) - 1.f);
            int klo = kt4 * 32 + kg * 8;
            #pragma unroll
            for (int ct = 0; ct < 8; ct++) {
                half8 bf = *(const half8*)&bs[ct * 16 + ln][klo];
                acc[ct] = __builtin_amdgcn_mfma_f32_16x16x32_f16(af, bf, acc[ct], 0, 0, 0);
            }
        }
        __syncthreads();
    }

    _Float16 (*tbuf)[16][136] = (_Float16 (*)[16][136])&bs[0][0];
    #pragma unroll
    for (int ct = 0; ct < 8; ct++)
        #pragma unroll
        for (int r = 0; r < 4; r++)
            tbuf[wid][kg * 4 + r][ct * 16 + ln] = (_Float16)acc[ct][r];
    __syncthreads();

    int rr = l >> 2, cq = l & 3;
    int node = n0w + rr;
    half8 hv[4];
    #pragma unroll
    for (int j = 0; j < 4; j++) hv[j] = *(const half8*)&tbuf[wid][rr][cq * 32 + j * 8];
    float ps = 0.f, pd = 0.f;
    #pragma unroll
    for (int j = 0; j < 4; j++) {
        int cb = cq * 32 + j * 8;
        float4 s0 = *(const float4*)&asw[cb], s1 = *(const float4*)&asw[cb + 4];
        float4 d0 = *(const float4*)&adw[cb], d1 = *(const float4*)&adw[cb + 4];
        ps = fmaf((float)hv[j][0], s0.x, ps); pd = fmaf((float)hv[j][0], d0.x, pd);
        ps = fmaf((float)hv[j][1], s0.y, ps); pd = fmaf((float)hv[j][1], d0.y, pd);
        ps = fmaf((float)hv[j][2], s0.z, ps); pd = fmaf((float)hv[j][2], d0.z, pd);
        ps = fmaf((float)hv[j][3], s0.w, ps); pd = fmaf((float)hv[j][3], d0.w, pd);
        ps = fmaf((float)hv[j][4], s1.x, ps); pd = fmaf((float)hv[j][4], d1.x, pd);
        ps = fmaf((float)hv[j][5], s1.y, ps); pd = fmaf((float)hv[j][5], d1.y, pd);
        ps = fmaf((float)hv[j][6], s1.z, ps); pd = fmaf((float)hv[j][6], d1.z, pd);
        ps = fmaf((float)hv[j][7], s1.w, ps); pd = fmaf((float)hv[j][7], d1.w, pd);
    }
    ps += __shfl_xor(ps, 1); ps += __shfl_xor(ps, 2);
    pd += __shfl_xor(pd, 1); pd += __shfl_xor(pd, 2);
    if (node < N) {
        #pragma unroll
        for (int j = 0; j < 4; j++)
            *(half8*)&g2h[(size_t)node * 128 + cq * 32 + j * 8] = hv[j];
        if (cq == 0) { as2[node] = ps; ad2[node] = pd; }
    }
}

// ---------- Layer 2 aggregation: wave per node; f16 output ----------
__global__ void k_agg2(const int* __restrict__ rp, const int* __restrict__ esrc,
                       const float* __restrict__ as2, const float* __restrict__ ad2,
                       const _Float16* __restrict__ g2h, const float* __restrict__ b2,
                       _Float16* __restrict__ out2h, int N) {
    int wid = threadIdx.x >> 6, lane = threadIdx.x & 63;
    int n = blockIdx.x * 4 + wid;
    if (n >= N) return;
    int beg = rp[n], end = rp[n + 1];
    float ad = ad2[n];
    float ax = 0.f, ay = 0.f, den = 0.f;
    for (int t0 = beg; t0 < end; t0 += 64) {
        int k = t0 + lane;
        int sl = 0; float wl = 0.f;
        if (k < end) {
            sl = esrc[k];
            float e = as2[sl] + ad;
            e = e > 0.f ? e : NEG_SLOPE * e;
            wl = __expf(e);
        }
        int nt = min(64, end - t0);
        for (int k2 = 0; k2 < nt; k2++) {
            float w = __shfl(wl, k2);
            int s = __shfl(sl, k2);
            half2v gv = ((const half2v*)g2h)[(size_t)s * 64 + lane];
            den += w;
            ax = fmaf(w, (float)gv[0], ax);
            ay = fmaf(w, (float)gv[1], ay);
        }
    }
    float inv = 1.f / (den + 1e-16f);
    float2 bv = ((const float2*)b2)[lane];
    half2v ov;
    ov[0] = (_Float16)(ax * inv + bv.x);
    ov[1] = (_Float16)(ay * inv + bv.y);
    ((half2v*)out2h)[(size_t)n * 64 + lane] = ov;
}

// ---------- BN2 stats (512-block streaming pass, f16 input) ----------
__global__ void k_bnstats(const _Float16* __restrict__ v, int N,
                          float* __restrict__ sum, float* __restrict__ sq) {
    int j = threadIdx.x;  // 128
    int rows = (N + gridDim.x - 1) / gridDim.x;
    int r0 = blockIdx.x * rows, r1 = min(N, r0 + rows);
    float s = 0.f, q = 0.f;
    for (int r = r0; r < r1; r++) {
        float t = (float)v[(size_t)r * 128 + j];
        s += t; q = fmaf(t, t, q);
    }
    atomicAdd(&sum[j], s);
    atomicAdd(&sq[j], q);
}

// ---------- pooling: partial sums with BN2+ELU and per-graph 1/count fused ----------
__global__ void k_poolpart(const _Float16* __restrict__ v, const int* __restrict__ batch,
                           const int* __restrict__ gb,
                           const float* __restrict__ bnsum, const float* __restrict__ bnsq,
                           const float* __restrict__ gamma, const float* __restrict__ beta,
                           float* __restrict__ out, int N, int rowsPerBlock) {
    int j = threadIdx.x;  // 128
    float mu = bnsum[j] / N;
    float var = bnsq[j] / N - mu * mu;
    float sc = rsqrtf(var + BN_EPS) * gamma[j];
    float sh = beta[j] - mu * sc;
    int r0 = blockIdx.x * rowsPerBlock;
    if (r0 >= N) return;
    int r1 = min(N, r0 + rowsPerBlock);
    int curg = batch[r0];
    float invc = 1.f / fmaxf((float)(gb[curg + 1] - gb[curg]), 1.0f);
    float acc = 0.f;
    for (int r = r0; r < r1; r++) {
        int g = batch[r];
        if (g != curg) {
            atomicAdd(&out[(size_t)curg * 128 + j], acc * invc);
            curg = g; acc = 0.f;
            invc = 1.f / fmaxf((float)(gb[curg + 1] - gb[curg]), 1.0f);
        }
        float y = fmaf((float)v[(size_t)r * 128 + j], sc, sh);
        acc += y > 0.f ? y : (__expf(y) - 1.0f);
    }
    atomicAdd(&out[(size_t)curg * 128 + j], acc * invc);
}

extern "C" void kernel_launch(void* const* d_in, const int* in_sizes, int n_in,
                              void* d_out, int out_size, void* d_ws, size_t ws_size,
                              hipStream_t stream) {
    const float* x     = (const float*)d_in[0];
    const int*   ei    = (const int*)d_in[1];
    const int*   batch = (const int*)d_in[2];
    const float* W1    = (const float*)d_in[4];
    const float* asw1  = (const float*)d_in[5];
    const float* adw1  = (const float*)d_in[6];
    const float* b1    = (const float*)d_in[7];
    const float* gamma1= (const float*)d_in[8];
    const float* beta1 = (const float*)d_in[9];
    const float* W2    = (const float*)d_in[10];
    const float* asw2  = (const float*)d_in[11];
    const float* adw2  = (const float*)d_in[12];
    const float* b2    = (const float*)d_in[13];
    const float* gamma2= (const float*)d_in[14];
    const float* beta2 = (const float*)d_in[15];
    float* out = (float*)d_out;

    const int N  = in_sizes[2];
    const int E  = in_sizes[1] / 2;
    const int E2 = E + N;
    const int G  = out_size / 128;

    char* ws = (char*)d_ws;
    size_t off = 0;
    auto A = [&](size_t bytes) { size_t o = off; off += (bytes + 255) & ~(size_t)255; return o; };
    _Float16* g2h  = (_Float16*)(ws + A((size_t)N * 128 * 2));
    _Float16* w2t  = (_Float16*)(ws + A((size_t)128 * 256 * 2));
    _Float16* out2h= (_Float16*)(ws + A((size_t)N * 128 * 2));
    float* uv    = (float*)(ws + A((size_t)N * 8 * 4));
    float* as2   = (float*)(ws + A((size_t)N * 4));
    float* ad2   = (float*)(ws + A((size_t)N * 4));
    float* coef  = (float*)(ws + A(16 * 4));
    int*   gb    = (int*)(ws + A((size_t)(G + 1) * 4));
    int*   rp    = (int*)(ws + A((size_t)(N + 1) * 4));
    int*   esrc  = (int*)(ws + A((size_t)E2 * 4));
    int*   bsums = (int*)(ws + A((size_t)((N + 1023) / 1024) * 4));
    // contiguous zero-region: cnt[N] | stats[20] | bnsum[256] | bnsq[256]
    size_t zbytes = ((size_t)N + 20 + 256 + 256) * 4;
    size_t zoff = A(zbytes);
    int*   cnt   = (int*)(ws + zoff);
    float* stats = (float*)(cnt + N);
    float* bnsum = stats + 20;
    float* bnsq  = bnsum + 256;

    const int nb = (N + 1023) / 1024;

    // 1: zero scratch AND the full output buffer (fixes replay accumulation)
    int n4 = (int)((zbytes + 15) / 16);
    int m4 = (out_size + 3) / 4;          // out_size floats -> uint4 count (out_size % 4 == 0)
    k_zero<<<(n4 + m4 + 255) / 256, 256, 0, stream>>>((uint4*)(ws + zoff), n4,
                                                      (uint4*)out, m4);

    // 2: setup (coef + gbounds + w2t + degree count)
    int degBlocks = (E2 + 255) / 256;
    k_setup<<<130 + degBlocks, 256, 0, stream>>>(W1, asw1, adw1, coef, W2, w2t,
                                                 batch, N, G, gb, ei, E, E2, cnt);

    // 3-4: hierarchical scan -> rp
    k_scan1<<<nb, 1024, 0, stream>>>(cnt, rp, bsums, N);
    k_scan2f<<<nb, 1024, 0, stream>>>(rp, bsums, N, E2, nb);

    // 5: scatter edges into CSR (consumes cnt back to zero)
    k_scatter<<<degBlocks, 256, 0, stream>>>(ei, E, E2, rp, cnt, esrc);

    // 6: layer-1 rank-2 aggregation + BN1 stats
    k_agg1r<<<(N + 255) / 256, 256, 0, stream>>>(rp, esrc, x, coef, uv, stats, N);

    // 7: layer-2 GEMM via MFMA (BN1 coef folded in-block)
    k_gemm2<<<(N + 63) / 64, 256, 0, stream>>>(uv, stats, W1, b1, gamma1, beta1,
                                               w2t, asw2, adw2, g2h, as2, ad2, N);

    // 8: layer-2 aggregation (wave per node, f16 out)
    k_agg2<<<(N + 3) / 4, 256, 0, stream>>>(rp, esrc, as2, ad2, g2h, b2, out2h, N);

    // 9: BN2 stats
    k_bnstats<<<512, 128, 0, stream>>>(out2h, N, bnsum, bnsq);

    // 10: pooling with fused BN2+ELU+1/count
    const int rowsPB = 64;
    k_poolpart<<<(N + rowsPB - 1) / rowsPB, 128, 0, stream>>>(out2h, batch, gb, bnsum, bnsq,
                                                              gamma2, beta2, out, N, rowsPB);
}

// Round 16
// 176.354 us; speedup vs baseline: 1.0696x; 1.0235x over previous
//
#include <hip/hip_runtime.h>
#include <hip/hip_bf16.h>

#define NEG_SLOPE 0.2f
#define BN_EPS 1e-5f

typedef _Float16 half8 __attribute__((ext_vector_type(8)));
typedef _Float16 half2v __attribute__((ext_vector_type(2)));
typedef float f32x4 __attribute__((ext_vector_type(4)));

// ---------- fast zero of scratch + output (both ranges, every call) ----------
__global__ void k_zero(uint4* __restrict__ p, int n4, uint4* __restrict__ q, int m4) {
    int i = blockIdx.x * blockDim.x + threadIdx.x;
    if (i < n4) p[i] = (uint4){0u, 0u, 0u, 0u};
    else if (i < n4 + m4) q[i - n4] = (uint4){0u, 0u, 0u, 0u};
}

// ---------- setup: coef (blk0), gbounds (blk1), w2t transpose (blk2..129),
//            edge degree count (blk130..) ----------
__global__ void k_setup(const float* __restrict__ W1, const float* __restrict__ asw,
                        const float* __restrict__ adw, float* __restrict__ coef,
                        const float* __restrict__ W2, _Float16* __restrict__ w2t,
                        const int* __restrict__ batch, int N, int G, int* __restrict__ gb,
                        const int* __restrict__ ei, int E, int E2, int* __restrict__ cnt) {
    int bid = blockIdx.x, t = threadIdx.x;
    if (bid == 0) {
        float w0 = W1[t], w1 = W1[256 + t], as = asw[t], ad = adw[t];
        float v0 = w0 * as, v1 = w1 * as, v2 = w0 * ad, v3 = w1 * ad;
        for (int o = 32; o; o >>= 1) {
            v0 += __shfl_down(v0, o); v1 += __shfl_down(v1, o);
            v2 += __shfl_down(v2, o); v3 += __shfl_down(v3, o);
        }
        if ((t & 63) == 0) {
            int h = t >> 6;
            coef[h * 4 + 0] = v0; coef[h * 4 + 1] = v1;
            coef[h * 4 + 2] = v2; coef[h * 4 + 3] = v3;
        }
    } else if (bid == 1) {
        int g = t;
        if (g <= G) {
            int lo = 0, hi = N;
            while (lo < hi) { int mid = (lo + hi) >> 1; if (batch[mid] < g) lo = mid + 1; else hi = mid; }
            gb[g] = lo;
        }
    } else if (bid < 130) {
        int c = bid - 2;                     // 0..127
        w2t[(size_t)c * 256 + t] = (_Float16)W2[(size_t)t * 128 + c];
    } else {
        int i = (bid - 130) * 256 + t;
        if (i < E2) {
            int d = (i < E) ? ei[E + i] : (i - E);
            atomicAdd(&cnt[d], 1);
        }
    }
}

// ---------- hierarchical scan, stage 1 ----------
__global__ void k_scan1(const int* __restrict__ cnt, int* __restrict__ rp,
                        int* __restrict__ bsums, int n) {
    __shared__ int s[1024];
    int i = blockIdx.x * 1024 + threadIdx.x;
    int v = (i < n) ? cnt[i] : 0;
    s[threadIdx.x] = v;
    __syncthreads();
    for (int o = 1; o < 1024; o <<= 1) {
        int t = (threadIdx.x >= o) ? s[threadIdx.x - o] : 0;
        __syncthreads();
        s[threadIdx.x] += t;
        __syncthreads();
    }
    if (i < n) rp[i] = s[threadIdx.x] - v;
    if (threadIdx.x == 1023) bsums[blockIdx.x] = s[1023];
}

// ---------- stage 2: wave-parallel prefix of bsums + offset add (nb <= 64) ----------
__global__ void k_scan2f(int* __restrict__ rp, const int* __restrict__ bsums,
                         int n, int total, int nb) {
    __shared__ int boff;
    if (threadIdx.x < 64) {
        int lane = threadIdx.x;
        int v = (lane < nb) ? bsums[lane] : 0;
        #pragma unroll
        for (int o = 1; o < 64; o <<= 1) {
            int t = __shfl_up(v, o);
            if (lane >= o) v += t;
        }
        int ex = __shfl_up(v, 1);
        if (lane == (int)blockIdx.x) boff = (blockIdx.x == 0) ? 0 : ex;
    }
    __syncthreads();
    int i = blockIdx.x * 1024 + threadIdx.x;
    if (i < n) rp[i] += boff;
    if (blockIdx.x == 0 && threadIdx.x == 0) rp[n] = total;
}

// ---------- scatter: consumes cnt (deg) via atomicSub ----------
__global__ void k_scatter(const int* __restrict__ ei, int E, int E2,
                          const int* __restrict__ rp, int* __restrict__ cnt,
                          int* __restrict__ esrc) {
    int i = blockIdx.x * blockDim.x + threadIdx.x;
    if (i >= E2) return;
    int s, d;
    if (i < E) { s = ei[i]; d = ei[E + i]; } else { s = d = i - E; }
    int old = atomicSub(&cnt[d], 1);
    esrc[rp[d] + old - 1] = s;
}

// ---------- Layer 1 aggregation (rank-2) + fused BN1 stats reduction ----------
__global__ void k_agg1r(const int* __restrict__ rp, const int* __restrict__ esrc,
                        const float* __restrict__ x, const float* __restrict__ coef,
                        float* __restrict__ uv, float* __restrict__ stats, int N) {
    __shared__ float sred[4][20];
    int tid = threadIdx.x, lane = tid & 63, wid = tid >> 6;
    int n = blockIdx.x * blockDim.x + tid;
    float st[20];
    #pragma unroll
    for (int i = 0; i < 20; i++) st[i] = 0.f;

    if (n < N) {
        float c[16];
        #pragma unroll
        for (int i = 0; i < 16; i++) c[i] = coef[i];
        float2 xn = ((const float2*)x)[n];
        float ad[4], den[4], sx[4], sy[4];
        #pragma unroll
        for (int h = 0; h < 4; h++) {
            ad[h] = fmaf(xn.x, c[h * 4 + 2], xn.y * c[h * 4 + 3]);
            den[h] = 0.f; sx[h] = 0.f; sy[h] = 0.f;
        }
        int beg = rp[n], end = rp[n + 1];
        for (int k = beg; k < end; k++) {
            int s = esrc[k];
            float2 xv = ((const float2*)x)[s];
            #pragma unroll
            for (int h = 0; h < 4; h++) {
                float e = fmaf(xv.x, c[h * 4 + 0], xv.y * c[h * 4 + 1]) + ad[h];
                e = e > 0.f ? e : NEG_SLOPE * e;
                float w = __expf(e);
                den[h] += w; sx[h] = fmaf(w, xv.x, sx[h]); sy[h] = fmaf(w, xv.y, sy[h]);
            }
        }
        float* o = uv + (size_t)n * 8;
        #pragma unroll
        for (int h = 0; h < 4; h++) {
            float inv = 1.f / (den[h] + 1e-16f);
            float u = sx[h] * inv, v = sy[h] * inv;
            o[h] = u; o[4 + h] = v;
            st[h] = u; st[4 + h] = v;
            st[8 + h] = u * u; st[12 + h] = v * v; st[16 + h] = u * v;
        }
    }
    #pragma unroll
    for (int i = 0; i < 20; i++)
        for (int o = 32; o; o >>= 1) st[i] += __shfl_down(st[i], o);
    if (lane == 0)
        #pragma unroll
        for (int i = 0; i < 20; i++) sred[wid][i] = st[i];
    __syncthreads();
    if (tid < 20)
        atomicAdd(&stats[tid], sred[0][tid] + sred[1][tid] + sred[2][tid] + sred[3][tid]);
}

// ---------- Layer 2 GEMM via MFMA; 512 threads / 128 rows per block ----------
__global__ __launch_bounds__(512) void k_gemm2(
        const float* __restrict__ uv, const float* __restrict__ stats,
        const float* __restrict__ W1, const float* __restrict__ b1,
        const float* __restrict__ gamma, const float* __restrict__ beta,
        const _Float16* __restrict__ w2t,
        const float* __restrict__ asw, const float* __restrict__ adw,
        _Float16* __restrict__ g2h, float* __restrict__ as2,
        float* __restrict__ ad2, int N) {
    __shared__ _Float16 bs[128][136];
    __shared__ float abcs[768];
    int tid = threadIdx.x, wid = tid >> 6, l = tid & 63;
    int kg = l >> 4, ln = l & 15;
    int n0w = blockIdx.x * 128 + wid * 16;

    if (tid < 256) {
        int j = tid, h = j >> 6;
        float w0 = W1[j], w1 = W1[256 + j], b = b1[j];
        float Su = stats[h], Sv = stats[4 + h], Suu = stats[8 + h],
              Svv = stats[12 + h], Suv = stats[16 + h];
        float fN = (float)N;
        float lin = fmaf(w0, Su, w1 * Sv);
        float mean = lin / fN + b;
        float sq = w0 * w0 * Suu + w1 * w1 * Svv + 2.f * w0 * w1 * Suv + 2.f * b * lin + fN * b * b;
        float var = sq / fN - mean * mean;
        float sc = rsqrtf(var + BN_EPS) * gamma[j];
        float sh = beta[j] - mean * sc;
        abcs[j] = sc * w0;
        abcs[256 + j] = sc * w1;
        abcs[512 + j] = fmaf(sc, b, sh);
    }

    int arow = n0w + ln;
    float uvr[8];
    if (arow < N) {
        const float4* p = (const float4*)(uv + (size_t)arow * 8);
        float4 t0 = p[0], t1 = p[1];
        uvr[0] = t0.x; uvr[1] = t0.y; uvr[2] = t0.z; uvr[3] = t0.w;
        uvr[4] = t1.x; uvr[5] = t1.y; uvr[6] = t1.z; uvr[7] = t1.w;
    } else {
        #pragma unroll
        for (int i = 0; i < 8; i++) uvr[i] = 0.f;
    }

    f32x4 acc[8];
    #pragma unroll
    for (int ct = 0; ct < 8; ct++) acc[ct] = (f32x4){0.f, 0.f, 0.f, 0.f};

    int sc_ = tid >> 2, q = tid & 3;       // 128 rows x 4 quarters
    for (int s = 0; s < 2; s++) {
        #pragma unroll
        for (int j = 0; j < 4; j++) {
            *(half8*)&bs[sc_][q * 32 + j * 8] =
                *(const half8*)&w2t[(size_t)sc_ * 256 + s * 128 + q * 32 + j * 8];
        }
        __syncthreads();
        #pragma unroll
        for (int kt4 = 0; kt4 < 4; kt4++) {
            int kt = s * 4 + kt4;
            int h = kt >> 1;
            float u = uvr[h], v = uvr[4 + h];
            int kb = kt * 32 + kg * 8;
            float4 A0a = *(const float4*)&abcs[kb],       A0b = *(const float4*)&abcs[kb + 4];
            float4 A1a = *(const float4*)&abcs[256 + kb], A1b = *(const float4*)&abcs[256 + kb + 4];
            float4 A2a = *(const float4*)&abcs[512 + kb], A2b = *(const float4*)&abcs[512 + kb + 4];
            half8 af;
            float y;
            y = fmaf(A0a.x, u, fmaf(A1a.x, v, A2a.x)); af[0] = (_Float16)(y > 0.f ? y : __expf(y) - 1.f);
            y = fmaf(A0a.y, u, fmaf(A1a.y, v, A2a.y)); af[1] = (_Float16)(y > 0.f ? y : __expf(y) - 1.f);
            y = fmaf(A0a.z, u, fmaf(A1a.z, v, A2a.z)); af[2] = (_Float16)(y > 0.f ? y : __expf(y) - 1.f);
            y = fmaf(A0a.w, u, fmaf(A1a.w, v, A2a.w)); af[3] = (_Float16)(y > 0.f ? y : __expf(y) - 1.f);
            y = fmaf(A0b.x, u, fmaf(A1b.x, v, A2b.x)); af[4] = (_Float16)(y > 0.f ? y : __expf(y) - 1.f);
            y = fmaf(A0b.y, u, fmaf(A1b.y, v, A2b.y)); af[5] = (_Float16)(y > 0.f ? y : __expf(y) - 1.f);
            y = fmaf(A0b.z, u, fmaf(A1b.z, v, A2b.z)); af[6] = (_Float16)(y > 0.f ? y : __expf(y) - 1.f);
            y = fmaf(A0b.w, u, fmaf(A1b.w, v, A2b.w)); af[7] = (_Float16)(y > 0.f ? y : __expf(y) - 1.f);
            int klo = kt4 * 32 + kg * 8;
            #pragma unroll
            for (int ct = 0; ct < 8; ct++) {
                half8 bf = *(const half8*)&bs[ct * 16 + ln][klo];
                acc[ct] = __builtin_amdgcn_mfma_f32_16x16x32_f16(af, bf, acc[ct], 0, 0, 0);
            }
        }
        __syncthreads();
    }

    // epilogue transpose: tbuf[8][16][136] exactly aliases bs (34816 B)
    _Float16 (*tbuf)[16][136] = (_Float16 (*)[16][136])&bs[0][0];
    #pragma unroll
    for (int ct = 0; ct < 8; ct++)
        #pragma unroll
        for (int r = 0; r < 4; r++)
            tbuf[wid][kg * 4 + r][ct * 16 + ln] = (_Float16)acc[ct][r];
    __syncthreads();

    int rr = l >> 2, cq = l & 3;
    int node = n0w + rr;
    half8 hv[4];
    #pragma unroll
    for (int j = 0; j < 4; j++) hv[j] = *(const half8*)&tbuf[wid][rr][cq * 32 + j * 8];
    float ps = 0.f, pd = 0.f;
    #pragma unroll
    for (int j = 0; j < 4; j++) {
        int cb = cq * 32 + j * 8;
        float4 s0 = *(const float4*)&asw[cb], s1 = *(const float4*)&asw[cb + 4];
        float4 d0 = *(const float4*)&adw[cb], d1 = *(const float4*)&adw[cb + 4];
        ps = fmaf((float)hv[j][0], s0.x, ps); pd = fmaf((float)hv[j][0], d0.x, pd);
        ps = fmaf((float)hv[j][1], s0.y, ps); pd = fmaf((float)hv[j][1], d0.y, pd);
        ps = fmaf((float)hv[j][2], s0.z, ps); pd = fmaf((float)hv[j][2], d0.z, pd);
        ps = fmaf((float)hv[j][3], s0.w, ps); pd = fmaf((float)hv[j][3], d0.w, pd);
        ps = fmaf((float)hv[j][4], s1.x, ps); pd = fmaf((float)hv[j][4], d1.x, pd);
        ps = fmaf((float)hv[j][5], s1.y, ps); pd = fmaf((float)hv[j][5], d1.y, pd);
        ps = fmaf((float)hv[j][6], s1.z, ps); pd = fmaf((float)hv[j][6], d1.z, pd);
        ps = fmaf((float)hv[j][7], s1.w, ps); pd = fmaf((float)hv[j][7], d1.w, pd);
    }
    ps += __shfl_xor(ps, 1); ps += __shfl_xor(ps, 2);
    pd += __shfl_xor(pd, 1); pd += __shfl_xor(pd, 2);
    if (node < N) {
        #pragma unroll
        for (int j = 0; j < 4; j++)
            *(half8*)&g2h[(size_t)node * 128 + cq * 32 + j * 8] = hv[j];
        if (cq == 0) { as2[node] = ps; ad2[node] = pd; }
    }
}

// ---------- Layer 2 aggregation: wave per node; f16 output ----------
__global__ void k_agg2(const int* __restrict__ rp, const int* __restrict__ esrc,
                       const float* __restrict__ as2, const float* __restrict__ ad2,
                       const _Float16* __restrict__ g2h, const float* __restrict__ b2,
                       _Float16* __restrict__ out2h, int N) {
    int wid = threadIdx.x >> 6, lane = threadIdx.x & 63;
    int n = blockIdx.x * 4 + wid;
    if (n >= N) return;
    int beg = rp[n], end = rp[n + 1];
    float ad = ad2[n];
    float ax = 0.f, ay = 0.f, den = 0.f;
    for (int t0 = beg; t0 < end; t0 += 64) {
        int k = t0 + lane;
        int sl = 0; float wl = 0.f;
        if (k < end) {
            sl = esrc[k];
            float e = as2[sl] + ad;
            e = e > 0.f ? e : NEG_SLOPE * e;
            wl = __expf(e);
        }
        int nt = min(64, end - t0);
        for (int k2 = 0; k2 < nt; k2++) {
            float w = __shfl(wl, k2);
            int s = __shfl(sl, k2);
            half2v gv = ((const half2v*)g2h)[(size_t)s * 64 + lane];
            den += w;
            ax = fmaf(w, (float)gv[0], ax);
            ay = fmaf(w, (float)gv[1], ay);
        }
    }
    float inv = 1.f / (den + 1e-16f);
    float2 bv = ((const float2*)b2)[lane];
    half2v ov;
    ov[0] = (_Float16)(ax * inv + bv.x);
    ov[1] = (_Float16)(ay * inv + bv.y);
    ((half2v*)out2h)[(size_t)n * 64 + lane] = ov;
}

// ---------- BN2 stats (1024-block streaming pass, f16 input) ----------
__global__ void k_bnstats(const _Float16* __restrict__ v, int N,
                          float* __restrict__ sum, float* __restrict__ sq) {
    int j = threadIdx.x;  // 128
    int rows = (N + gridDim.x - 1) / gridDim.x;
    int r0 = blockIdx.x * rows, r1 = min(N, r0 + rows);
    float s = 0.f, q = 0.f;
    for (int r = r0; r < r1; r++) {
        float t = (float)v[(size_t)r * 128 + j];
        s += t; q = fmaf(t, t, q);
    }
    atomicAdd(&sum[j], s);
    atomicAdd(&sq[j], q);
}

// ---------- pooling: partial sums with BN2+ELU and per-graph 1/count fused ----------
__global__ void k_poolpart(const _Float16* __restrict__ v, const int* __restrict__ batch,
                           const int* __restrict__ gb,
                           const float* __restrict__ bnsum, const float* __restrict__ bnsq,
                           const float* __restrict__ gamma, const float* __restrict__ beta,
                           float* __restrict__ out, int N, int rowsPerBlock) {
    int j = threadIdx.x;  // 128
    float mu = bnsum[j] / N;
    float var = bnsq[j] / N - mu * mu;
    float sc = rsqrtf(var + BN_EPS) * gamma[j];
    float sh = beta[j] - mu * sc;
    int r0 = blockIdx.x * rowsPerBlock;
    if (r0 >= N) return;
    int r1 = min(N, r0 + rowsPerBlock);
    int curg = batch[r0];
    float invc = 1.f / fmaxf((float)(gb[curg + 1] - gb[curg]), 1.0f);
    float acc = 0.f;
    for (int r = r0; r < r1; r++) {
        int g = batch[r];
        if (g != curg) {
            atomicAdd(&out[(size_t)curg * 128 + j], acc * invc);
            curg = g; acc = 0.f;
            invc = 1.f / fmaxf((float)(gb[curg + 1] - gb[curg]), 1.0f);
        }
        float y = fmaf((float)v[(size_t)r * 128 + j], sc, sh);
        acc += y > 0.f ? y : (__expf(y) - 1.0f);
    }
    atomicAdd(&out[(size_t)curg * 128 + j], acc * invc);
}

extern "C" void kernel_launch(void* const* d_in, const int* in_sizes, int n_in,
                              void* d_out, int out_size, void* d_ws, size_t ws_size,
                              hipStream_t stream) {
    const float* x     = (const float*)d_in[0];
    const int*   ei    = (const int*)d_in[1];
    const int*   batch = (const int*)d_in[2];
    const float* W1    = (const float*)d_in[4];
    const float* asw1  = (const float*)d_in[5];
    const float* adw1  = (const float*)d_in[6];
    const float* b1    = (const float*)d_in[7];
    const float* gamma1= (const float*)d_in[8];
    const float* beta1 = (const float*)d_in[9];
    const float* W2    = (const float*)d_in[10];
    const float* asw2  = (const float*)d_in[11];
    const float* adw2  = (const float*)d_in[12];
    const float* b2    = (const float*)d_in[13];
    const float* gamma2= (const float*)d_in[14];
    const float* beta2 = (const float*)d_in[15];
    float* out = (float*)d_out;

    const int N  = in_sizes[2];
    const int E  = in_sizes[1] / 2;
    const int E2 = E + N;
    const int G  = out_size / 128;

    char* ws = (char*)d_ws;
    size_t off = 0;
    auto A = [&](size_t bytes) { size_t o = off; off += (bytes + 255) & ~(size_t)255; return o; };
    _Float16* g2h  = (_Float16*)(ws + A((size_t)N * 128 * 2));
    _Float16* w2t  = (_Float16*)(ws + A((size_t)128 * 256 * 2));
    _Float16* out2h= (_Float16*)(ws + A((size_t)N * 128 * 2));
    float* uv    = (float*)(ws + A((size_t)N * 8 * 4));
    float* as2   = (float*)(ws + A((size_t)N * 4));
    float* ad2   = (float*)(ws + A((size_t)N * 4));
    float* coef  = (float*)(ws + A(16 * 4));
    int*   gb    = (int*)(ws + A((size_t)(G + 1) * 4));
    int*   rp    = (int*)(ws + A((size_t)(N + 1) * 4));
    int*   esrc  = (int*)(ws + A((size_t)E2 * 4));
    int*   bsums = (int*)(ws + A((size_t)((N + 1023) / 1024) * 4));
    // contiguous zero-region: cnt[N] | stats[20] | bnsum[256] | bnsq[256]
    size_t zbytes = ((size_t)N + 20 + 256 + 256) * 4;
    size_t zoff = A(zbytes);
    int*   cnt   = (int*)(ws + zoff);
    float* stats = (float*)(cnt + N);
    float* bnsum = stats + 20;
    float* bnsq  = bnsum + 256;

    const int nb = (N + 1023) / 1024;

    // 1: zero scratch AND the full output buffer
    int n4 = (int)((zbytes + 15) / 16);
    int m4 = (out_size + 3) / 4;
    k_zero<<<(n4 + m4 + 255) / 256, 256, 0, stream>>>((uint4*)(ws + zoff), n4,
                                                      (uint4*)out, m4);

    // 2: setup (coef + gbounds + w2t + degree count)
    int degBlocks = (E2 + 255) / 256;
    k_setup<<<130 + degBlocks, 256, 0, stream>>>(W1, asw1, adw1, coef, W2, w2t,
                                                 batch, N, G, gb, ei, E, E2, cnt);

    // 3-4: hierarchical scan -> rp
    k_scan1<<<nb, 1024, 0, stream>>>(cnt, rp, bsums, N);
    k_scan2f<<<nb, 1024, 0, stream>>>(rp, bsums, N, E2, nb);

    // 5: scatter edges into CSR (consumes cnt back to zero)
    k_scatter<<<degBlocks, 256, 0, stream>>>(ei, E, E2, rp, cnt, esrc);

    // 6: layer-1 rank-2 aggregation + BN1 stats
    k_agg1r<<<(N + 255) / 256, 256, 0, stream>>>(rp, esrc, x, coef, uv, stats, N);

    // 7: layer-2 GEMM via MFMA (512 threads / 128 rows per block)
    k_gemm2<<<(N + 127) / 128, 512, 0, stream>>>(uv, stats, W1, b1, gamma1, beta1,
                                                 w2t, asw2, adw2, g2h, as2, ad2, N);

    // 8: layer-2 aggregation (wave per node, f16 out)
    k_agg2<<<(N + 3) / 4, 256, 0, stream>>>(rp, esrc, as2, ad2, g2h, b2, out2h, N);

    // 9: BN2 stats (more TLP)
    k_bnstats<<<1024, 128, 0, stream>>>(out2h, N, bnsum, bnsq);

    // 10: pooling with fused BN2+ELU+1/count (more TLP)
    const int rowsPB = 32;
    k_poolpart<<<(N + rowsPB - 1) / rowsPB, 128, 0, stream>>>(out2h, batch, gb, bnsum, bnsq,
                                                              gamma2, beta2, out, N, rowsPB);
}

// Round 17
// 143.590 us; speedup vs baseline: 1.3137x; 1.2282x over previous
//
#include <hip/hip_runtime.h>
#include <hip/hip_bf16.h>

#define NEG_SLOPE 0.2f
#define BN_EPS 1e-5f

typedef _Float16 half8 __attribute__((ext_vector_type(8)));
typedef _Float16 half2v __attribute__((ext_vector_type(2)));
typedef float f32x4 __attribute__((ext_vector_type(4)));

// ---------- fast zero of scratch + output ----------
__global__ void k_zero(uint4* __restrict__ p, int n4, uint4* __restrict__ q, int m4) {
    int i = blockIdx.x * blockDim.x + threadIdx.x;
    if (i < n4) p[i] = (uint4){0u, 0u, 0u, 0u};
    else if (i < n4 + m4) q[i - n4] = (uint4){0u, 0u, 0u, 0u};
}

// ---------- setup: coef (blk0), gbounds (blk1), w2t transpose (blk2..129),
//            edge degree count (blk130..) ----------
__global__ void k_setup(const float* __restrict__ W1, const float* __restrict__ asw,
                        const float* __restrict__ adw, float* __restrict__ coef,
                        const float* __restrict__ W2, _Float16* __restrict__ w2t,
                        const int* __restrict__ batch, int N, int G, int* __restrict__ gb,
                        const int* __restrict__ ei, int E, int E2, int* __restrict__ cnt) {
    int bid = blockIdx.x, t = threadIdx.x;
    if (bid == 0) {
        float w0 = W1[t], w1 = W1[256 + t], as = asw[t], ad = adw[t];
        float v0 = w0 * as, v1 = w1 * as, v2 = w0 * ad, v3 = w1 * ad;
        for (int o = 32; o; o >>= 1) {
            v0 += __shfl_down(v0, o); v1 += __shfl_down(v1, o);
            v2 += __shfl_down(v2, o); v3 += __shfl_down(v3, o);
        }
        if ((t & 63) == 0) {
            int h = t >> 6;
            coef[h * 4 + 0] = v0; coef[h * 4 + 1] = v1;
            coef[h * 4 + 2] = v2; coef[h * 4 + 3] = v3;
        }
    } else if (bid == 1) {
        int g = t;
        if (g <= G) {
            int lo = 0, hi = N;
            while (lo < hi) { int mid = (lo + hi) >> 1; if (batch[mid] < g) lo = mid + 1; else hi = mid; }
            gb[g] = lo;
        }
    } else if (bid < 130) {
        int c = bid - 2;
        w2t[(size_t)c * 256 + t] = (_Float16)W2[(size_t)t * 128 + c];
    } else {
        int i = (bid - 130) * 256 + t;
        if (i < E2) {
            int d = (i < E) ? ei[E + i] : (i - E);
            atomicAdd(&cnt[d], 1);
        }
    }
}

// ---------- hierarchical scan, stage 1 ----------
__global__ void k_scan1(const int* __restrict__ cnt, int* __restrict__ rp,
                        int* __restrict__ bsums, int n) {
    __shared__ int s[1024];
    int i = blockIdx.x * 1024 + threadIdx.x;
    int v = (i < n) ? cnt[i] : 0;
    s[threadIdx.x] = v;
    __syncthreads();
    for (int o = 1; o < 1024; o <<= 1) {
        int t = (threadIdx.x >= o) ? s[threadIdx.x - o] : 0;
        __syncthreads();
        s[threadIdx.x] += t;
        __syncthreads();
    }
    if (i < n) rp[i] = s[threadIdx.x] - v;
    if (threadIdx.x == 1023) bsums[blockIdx.x] = s[1023];
}

// ---------- stage 2: wave-parallel prefix of bsums + offset add (nb <= 64) ----------
__global__ void k_scan2f(int* __restrict__ rp, const int* __restrict__ bsums,
                         int n, int total, int nb) {
    __shared__ int boff;
    if (threadIdx.x < 64) {
        int lane = threadIdx.x;
        int v = (lane < nb) ? bsums[lane] : 0;
        #pragma unroll
        for (int o = 1; o < 64; o <<= 1) {
            int t = __shfl_up(v, o);
            if (lane >= o) v += t;
        }
        int ex = __shfl_up(v, 1);
        if (lane == (int)blockIdx.x) boff = (blockIdx.x == 0) ? 0 : ex;
    }
    __syncthreads();
    int i = blockIdx.x * 1024 + threadIdx.x;
    if (i < n) rp[i] += boff;
    if (blockIdx.x == 0 && threadIdx.x == 0) rp[n] = total;
}

// ---------- scatter: consumes cnt (deg) via atomicSub ----------
__global__ void k_scatter(const int* __restrict__ ei, int E, int E2,
                          const int* __restrict__ rp, int* __restrict__ cnt,
                          int* __restrict__ esrc) {
    int i = blockIdx.x * blockDim.x + threadIdx.x;
    if (i >= E2) return;
    int s, d;
    if (i < E) { s = ei[i]; d = ei[E + i]; } else { s = d = i - E; }
    int old = atomicSub(&cnt[d], 1);
    esrc[rp[d] + old - 1] = s;
}

// ---------- Layer 1 aggregation (rank-2) + fused BN1 stats reduction ----------
__global__ void k_agg1r(const int* __restrict__ rp, const int* __restrict__ esrc,
                        const float* __restrict__ x, const float* __restrict__ coef,
                        float* __restrict__ uv, float* __restrict__ stats, int N) {
    __shared__ float sred[4][20];
    int tid = threadIdx.x, lane = tid & 63, wid = tid >> 6;
    int n = blockIdx.x * blockDim.x + tid;
    float st[20];
    #pragma unroll
    for (int i = 0; i < 20; i++) st[i] = 0.f;

    if (n < N) {
        float c[16];
        #pragma unroll
        for (int i = 0; i < 16; i++) c[i] = coef[i];
        float2 xn = ((const float2*)x)[n];
        float ad[4], den[4], sx[4], sy[4];
        #pragma unroll
        for (int h = 0; h < 4; h++) {
            ad[h] = fmaf(xn.x, c[h * 4 + 2], xn.y * c[h * 4 + 3]);
            den[h] = 0.f; sx[h] = 0.f; sy[h] = 0.f;
        }
        int beg = rp[n], end = rp[n + 1];
        for (int k = beg; k < end; k++) {
            int s = esrc[k];
            float2 xv = ((const float2*)x)[s];
            #pragma unroll
            for (int h = 0; h < 4; h++) {
                float e = fmaf(xv.x, c[h * 4 + 0], xv.y * c[h * 4 + 1]) + ad[h];
                e = e > 0.f ? e : NEG_SLOPE * e;
                float w = __expf(e);
                den[h] += w; sx[h] = fmaf(w, xv.x, sx[h]); sy[h] = fmaf(w, xv.y, sy[h]);
            }
        }
        float* o = uv + (size_t)n * 8;
        #pragma unroll
        for (int h = 0; h < 4; h++) {
            float inv = 1.f / (den[h] + 1e-16f);
            float u = sx[h] * inv, v = sy[h] * inv;
            o[h] = u; o[4 + h] = v;
            st[h] = u; st[4 + h] = v;
            st[8 + h] = u * u; st[12 + h] = v * v; st[16 + h] = u * v;
        }
    }
    #pragma unroll
    for (int i = 0; i < 20; i++)
        for (int o = 32; o; o >>= 1) st[i] += __shfl_down(st[i], o);
    if (lane == 0)
        #pragma unroll
        for (int i = 0; i < 20; i++) sred[wid][i] = st[i];
    __syncthreads();
    if (tid < 20)
        atomicAdd(&stats[tid], sred[0][tid] + sred[1][tid] + sred[2][tid] + sred[3][tid]);
}

// ---------- Layer 2 GEMM via MFMA; 512 threads / 128 rows per block ----------
__global__ __launch_bounds__(512) void k_gemm2(
        const float* __restrict__ uv, const float* __restrict__ stats,
        const float* __restrict__ W1, const float* __restrict__ b1,
        const float* __restrict__ gamma, const float* __restrict__ beta,
        const _Float16* __restrict__ w2t,
        const float* __restrict__ asw, const float* __restrict__ adw,
        _Float16* __restrict__ g2h, float* __restrict__ as2,
        float* __restrict__ ad2, int N) {
    __shared__ _Float16 bs[128][136];
    __shared__ float abcs[768];
    int tid = threadIdx.x, wid = tid >> 6, l = tid & 63;
    int kg = l >> 4, ln = l & 15;
    int n0w = blockIdx.x * 128 + wid * 16;

    if (tid < 256) {
        int j = tid, h = j >> 6;
        float w0 = W1[j], w1 = W1[256 + j], b = b1[j];
        float Su = stats[h], Sv = stats[4 + h], Suu = stats[8 + h],
              Svv = stats[12 + h], Suv = stats[16 + h];
        float fN = (float)N;
        float lin = fmaf(w0, Su, w1 * Sv);
        float mean = lin / fN + b;
        float sq = w0 * w0 * Suu + w1 * w1 * Svv + 2.f * w0 * w1 * Suv + 2.f * b * lin + fN * b * b;
        float var = sq / fN - mean * mean;
        float sc = rsqrtf(var + BN_EPS) * gamma[j];
        float sh = beta[j] - mean * sc;
        abcs[j] = sc * w0;
        abcs[256 + j] = sc * w1;
        abcs[512 + j] = fmaf(sc, b, sh);
    }

    int arow = n0w + ln;
    float uvr[8];
    if (arow < N) {
        const float4* p = (const float4*)(uv + (size_t)arow * 8);
        float4 t0 = p[0], t1 = p[1];
        uvr[0] = t0.x; uvr[1] = t0.y; uvr[2] = t0.z; uvr[3] = t0.w;
        uvr[4] = t1.x; uvr[5] = t1.y; uvr[6] = t1.z; uvr[7] = t1.w;
    } else {
        #pragma unroll
        for (int i = 0; i < 8; i++) uvr[i] = 0.f;
    }

    f32x4 acc[8];
    #pragma unroll
    for (int ct = 0; ct < 8; ct++) acc[ct] = (f32x4){0.f, 0.f, 0.f, 0.f};

    int sc_ = tid >> 2, q = tid & 3;
    for (int s = 0; s < 2; s++) {
        #pragma unroll
        for (int j = 0; j < 4; j++) {
            *(half8*)&bs[sc_][q * 32 + j * 8] =
                *(const half8*)&w2t[(size_t)sc_ * 256 + s * 128 + q * 32 + j * 8];
        }
        __syncthreads();
        #pragma unroll
        for (int kt4 = 0; kt4 < 4; kt4++) {
            int kt = s * 4 + kt4;
            int h = kt >> 1;
            float u = uvr[h], v = uvr[4 + h];
            int kb = kt * 32 + kg * 8;
            float4 A0a = *(const float4*)&abcs[kb],       A0b = *(const float4*)&abcs[kb + 4];
            float4 A1a = *(const float4*)&abcs[256 + kb], A1b = *(const float4*)&abcs[256 + kb + 4];
            float4 A2a = *(const float4*)&abcs[512 + kb], A2b = *(const float4*)&abcs[512 + kb + 4];
            half8 af;
            float y;
            y = fmaf(A0a.x, u, fmaf(A1a.x, v, A2a.x)); af[0] = (_Float16)(y > 0.f ? y : __expf(y) - 1.f);
            y = fmaf(A0a.y, u, fmaf(A1a.y, v, A2a.y)); af[1] = (_Float16)(y > 0.f ? y : __expf(y) - 1.f);
            y = fmaf(A0a.z, u, fmaf(A1a.z, v, A2a.z)); af[2] = (_Float16)(y > 0.f ? y : __expf(y) - 1.f);
            y = fmaf(A0a.w, u, fmaf(A1a.w, v, A2a.w)); af[3] = (_Float16)(y > 0.f ? y : __expf(y) - 1.f);
            y = fmaf(A0b.x, u, fmaf(A1b.x, v, A2b.x)); af[4] = (_Float16)(y > 0.f ? y : __expf(y) - 1.f);
            y = fmaf(A0b.y, u, fmaf(A1b.y, v, A2b.y)); af[5] = (_Float16)(y > 0.f ? y : __expf(y) - 1.f);
            y = fmaf(A0b.z, u, fmaf(A1b.z, v, A2b.z)); af[6] = (_Float16)(y > 0.f ? y : __expf(y) - 1.f);
            y = fmaf(A0b.w, u, fmaf(A1b.w, v, A2b.w)); af[7] = (_Float16)(y > 0.f ? y : __expf(y) - 1.f);
            int klo = kt4 * 32 + kg * 8;
            #pragma unroll
            for (int ct = 0; ct < 8; ct++) {
                half8 bf = *(const half8*)&bs[ct * 16 + ln][klo];
                acc[ct] = __builtin_amdgcn_mfma_f32_16x16x32_f16(af, bf, acc[ct], 0, 0, 0);
            }
        }
        __syncthreads();
    }

    _Float16 (*tbuf)[16][136] = (_Float16 (*)[16][136])&bs[0][0];
    #pragma unroll
    for (int ct = 0; ct < 8; ct++)
        #pragma unroll
        for (int r = 0; r < 4; r++)
            tbuf[wid][kg * 4 + r][ct * 16 + ln] = (_Float16)acc[ct][r];
    __syncthreads();

    int rr = l >> 2, cq = l & 3;
    int node = n0w + rr;
    half8 hv[4];
    #pragma unroll
    for (int j = 0; j < 4; j++) hv[j] = *(const half8*)&tbuf[wid][rr][cq * 32 + j * 8];
    float ps = 0.f, pd = 0.f;
    #pragma unroll
    for (int j = 0; j < 4; j++) {
        int cb = cq * 32 + j * 8;
        float4 s0 = *(const float4*)&asw[cb], s1 = *(const float4*)&asw[cb + 4];
        float4 d0 = *(const float4*)&adw[cb], d1 = *(const float4*)&adw[cb + 4];
        ps = fmaf((float)hv[j][0], s0.x, ps); pd = fmaf((float)hv[j][0], d0.x, pd);
        ps = fmaf((float)hv[j][1], s0.y, ps); pd = fmaf((float)hv[j][1], d0.y, pd);
        ps = fmaf((float)hv[j][2], s0.z, ps); pd = fmaf((float)hv[j][2], d0.z, pd);
        ps = fmaf((float)hv[j][3], s0.w, ps); pd = fmaf((float)hv[j][3], d0.w, pd);
        ps = fmaf((float)hv[j][4], s1.x, ps); pd = fmaf((float)hv[j][4], d1.x, pd);
        ps = fmaf((float)hv[j][5], s1.y, ps); pd = fmaf((float)hv[j][5], d1.y, pd);
        ps = fmaf((float)hv[j][6], s1.z, ps); pd = fmaf((float)hv[j][6], d1.z, pd);
        ps = fmaf((float)hv[j][7], s1.w, ps); pd = fmaf((float)hv[j][7], d1.w, pd);
    }
    ps += __shfl_xor(ps, 1); ps += __shfl_xor(ps, 2);
    pd += __shfl_xor(pd, 1); pd += __shfl_xor(pd, 2);
    if (node < N) {
        #pragma unroll
        for (int j = 0; j < 4; j++)
            *(half8*)&g2h[(size_t)node * 128 + cq * 32 + j * 8] = hv[j];
        if (cq == 0) { as2[node] = ps; ad2[node] = pd; }
    }
}

// ---------- Layer 2 aggregation: wave per node; f16 output ----------
__global__ void k_agg2(const int* __restrict__ rp, const int* __restrict__ esrc,
                       const float* __restrict__ as2, const float* __restrict__ ad2,
                       const _Float16* __restrict__ g2h, const float* __restrict__ b2,
                       _Float16* __restrict__ out2h, int N) {
    int wid = threadIdx.x >> 6, lane = threadIdx.x & 63;
    int n = blockIdx.x * 4 + wid;
    if (n >= N) return;
    int beg = rp[n], end = rp[n + 1];
    float ad = ad2[n];
    float ax = 0.f, ay = 0.f, den = 0.f;
    for (int t0 = beg; t0 < end; t0 += 64) {
        int k = t0 + lane;
        int sl = 0; float wl = 0.f;
        if (k < end) {
            sl = esrc[k];
            float e = as2[sl] + ad;
            e = e > 0.f ? e : NEG_SLOPE * e;
            wl = __expf(e);
        }
        int nt = min(64, end - t0);
        for (int k2 = 0; k2 < nt; k2++) {
            float w = __shfl(wl, k2);
            int s = __shfl(sl, k2);
            half2v gv = ((const half2v*)g2h)[(size_t)s * 64 + lane];
            den += w;
            ax = fmaf(w, (float)gv[0], ax);
            ay = fmaf(w, (float)gv[1], ay);
        }
    }
    float inv = 1.f / (den + 1e-16f);
    float2 bv = ((const float2*)b2)[lane];
    half2v ov;
    ov[0] = (_Float16)(ax * inv + bv.x);
    ov[1] = (_Float16)(ay * inv + bv.y);
    ((half2v*)out2h)[(size_t)n * 64 + lane] = ov;
}

// ---------- BN2 stats: vectorized half8 loads, 16 rowlanes x 16 colgroups ----------
__global__ void k_bnstats(const _Float16* __restrict__ v, int N,
                          float* __restrict__ sum, float* __restrict__ sq) {
    __shared__ float wred[4][16][16];
    int t = threadIdx.x;              // 256
    int rr = t >> 4, cg = t & 15;
    int rows = (N + gridDim.x - 1) / gridDim.x;
    int r0 = blockIdx.x * rows, r1 = min(N, r0 + rows);
    float s[8], q[8];
    #pragma unroll
    for (int i = 0; i < 8; i++) { s[i] = 0.f; q[i] = 0.f; }
    for (int r = r0 + rr; r < r1; r += 16) {
        half8 hv = *(const half8*)&v[(size_t)r * 128 + cg * 8];
        #pragma unroll
        for (int i = 0; i < 8; i++) {
            float xx = (float)hv[i];
            s[i] += xx; q[i] = fmaf(xx, xx, q[i]);
        }
    }
    // in-wave reduce over row-lanes (lane bits 4,5)
    #pragma unroll
    for (int i = 0; i < 8; i++) {
        s[i] += __shfl_xor(s[i], 16); s[i] += __shfl_xor(s[i], 32);
        q[i] += __shfl_xor(q[i], 16); q[i] += __shfl_xor(q[i], 32);
    }
    int wave = t >> 6, lane = t & 63;
    if (lane < 16) {
        #pragma unroll
        for (int i = 0; i < 8; i++) {
            wred[wave][lane][i] = s[i];
            wred[wave][lane][8 + i] = q[i];
        }
    }
    __syncthreads();
    {
        int cg2 = t >> 4, e = t & 15;
        float tot = wred[0][cg2][e] + wred[1][cg2][e] + wred[2][cg2][e] + wred[3][cg2][e];
        if (e < 8) atomicAdd(&sum[cg2 * 8 + e], tot);
        else       atomicAdd(&sq[cg2 * 8 + e - 8], tot);
    }
}

// ---------- pooling: one block per (graph, quarter); vectorized; BN2+ELU+1/c fused ----------
__global__ void k_poolg2(const _Float16* __restrict__ v, const int* __restrict__ gb,
                         const float* __restrict__ bnsum, const float* __restrict__ bnsq,
                         const float* __restrict__ gamma, const float* __restrict__ beta,
                         float* __restrict__ out, int N) {
    __shared__ float wred[4][16][8];
    int t = threadIdx.x;              // 256
    int g = blockIdx.x >> 2, qtr = blockIdx.x & 3;
    int rr = t >> 4, cg = t & 15;
    int gs = gb[g], ge = gb[g + 1];
    int len = ge - gs;
    int q0 = gs + (len * qtr) / 4, q1 = gs + (len * (qtr + 1)) / 4;
    float sc[8], sh[8];
    #pragma unroll
    for (int i = 0; i < 8; i++) {
        int j = cg * 8 + i;
        float mu = bnsum[j] / N;
        float var = bnsq[j] / N - mu * mu;
        sc[i] = rsqrtf(var + BN_EPS) * gamma[j];
        sh[i] = beta[j] - mu * sc[i];
    }
    float acc[8];
    #pragma unroll
    for (int i = 0; i < 8; i++) acc[i] = 0.f;
    for (int r = q0 + rr; r < q1; r += 16) {
        half8 hv = *(const half8*)&v[(size_t)r * 128 + cg * 8];
        #pragma unroll
        for (int i = 0; i < 8; i++) {
            float y = fmaf((float)hv[i], sc[i], sh[i]);
            acc[i] += y > 0.f ? y : (__expf(y) - 1.0f);
        }
    }
    #pragma unroll
    for (int i = 0; i < 8; i++) {
        acc[i] += __shfl_xor(acc[i], 16);
        acc[i] += __shfl_xor(acc[i], 32);
    }
    int wave = t >> 6, lane = t & 63;
    if (lane < 16) {
        #pragma unroll
        for (int i = 0; i < 8; i++) wred[wave][lane][i] = acc[i];
    }
    __syncthreads();
    if (t < 128) {
        int cg2 = t >> 3, e = t & 7;
        float tot = wred[0][cg2][e] + wred[1][cg2][e] + wred[2][cg2][e] + wred[3][cg2][e];
        float invc = 1.f / fmaxf((float)len, 1.0f);
        atomicAdd(&out[(size_t)g * 128 + cg2 * 8 + e], tot * invc);
    }
}

extern "C" void kernel_launch(void* const* d_in, const int* in_sizes, int n_in,
                              void* d_out, int out_size, void* d_ws, size_t ws_size,
                              hipStream_t stream) {
    const float* x     = (const float*)d_in[0];
    const int*   ei    = (const int*)d_in[1];
    const int*   batch = (const int*)d_in[2];
    const float* W1    = (const float*)d_in[4];
    const float* asw1  = (const float*)d_in[5];
    const float* adw1  = (const float*)d_in[6];
    const float* b1    = (const float*)d_in[7];
    const float* gamma1= (const float*)d_in[8];
    const float* beta1 = (const float*)d_in[9];
    const float* W2    = (const float*)d_in[10];
    const float* asw2  = (const float*)d_in[11];
    const float* adw2  = (const float*)d_in[12];
    const float* b2    = (const float*)d_in[13];
    const float* gamma2= (const float*)d_in[14];
    const float* beta2 = (const float*)d_in[15];
    float* out = (float*)d_out;

    const int N  = in_sizes[2];
    const int E  = in_sizes[1] / 2;
    const int E2 = E + N;
    const int G  = out_size / 128;

    char* ws = (char*)d_ws;
    size_t off = 0;
    auto A = [&](size_t bytes) { size_t o = off; off += (bytes + 255) & ~(size_t)255; return o; };
    _Float16* g2h  = (_Float16*)(ws + A((size_t)N * 128 * 2));
    _Float16* w2t  = (_Float16*)(ws + A((size_t)128 * 256 * 2));
    _Float16* out2h= (_Float16*)(ws + A((size_t)N * 128 * 2));
    float* uv    = (float*)(ws + A((size_t)N * 8 * 4));
    float* as2   = (float*)(ws + A((size_t)N * 4));
    float* ad2   = (float*)(ws + A((size_t)N * 4));
    float* coef  = (float*)(ws + A(16 * 4));
    int*   gb    = (int*)(ws + A((size_t)(G + 1) * 4));
    int*   rp    = (int*)(ws + A((size_t)(N + 1) * 4));
    int*   esrc  = (int*)(ws + A((size_t)E2 * 4));
    int*   bsums = (int*)(ws + A((size_t)((N + 1023) / 1024) * 4));
    size_t zbytes = ((size_t)N + 20 + 256 + 256) * 4;
    size_t zoff = A(zbytes);
    int*   cnt   = (int*)(ws + zoff);
    float* stats = (float*)(cnt + N);
    float* bnsum = stats + 20;
    float* bnsq  = bnsum + 256;

    const int nb = (N + 1023) / 1024;

    // 1: zero scratch AND the full output buffer
    int n4 = (int)((zbytes + 15) / 16);
    int m4 = (out_size + 3) / 4;
    k_zero<<<(n4 + m4 + 255) / 256, 256, 0, stream>>>((uint4*)(ws + zoff), n4,
                                                      (uint4*)out, m4);

    // 2: setup
    int degBlocks = (E2 + 255) / 256;
    k_setup<<<130 + degBlocks, 256, 0, stream>>>(W1, asw1, adw1, coef, W2, w2t,
                                                 batch, N, G, gb, ei, E, E2, cnt);

    // 3-4: hierarchical scan -> rp
    k_scan1<<<nb, 1024, 0, stream>>>(cnt, rp, bsums, N);
    k_scan2f<<<nb, 1024, 0, stream>>>(rp, bsums, N, E2, nb);

    // 5: scatter
    k_scatter<<<degBlocks, 256, 0, stream>>>(ei, E, E2, rp, cnt, esrc);

    // 6: layer-1 rank-2 aggregation + BN1 stats
    k_agg1r<<<(N + 255) / 256, 256, 0, stream>>>(rp, esrc, x, coef, uv, stats, N);

    // 7: layer-2 GEMM via MFMA
    k_gemm2<<<(N + 127) / 128, 512, 0, stream>>>(uv, stats, W1, b1, gamma1, beta1,
                                                 w2t, asw2, adw2, g2h, as2, ad2, N);

    // 8: layer-2 aggregation
    k_agg2<<<(N + 3) / 4, 256, 0, stream>>>(rp, esrc, as2, ad2, g2h, b2, out2h, N);

    // 9: BN2 stats (vectorized half8)
    k_bnstats<<<512, 256, 0, stream>>>(out2h, N, bnsum, bnsq);

    // 10: pooling (vectorized half8, block per graph-quarter)
    k_poolg2<<<G * 4, 256, 0, stream>>>(out2h, gb, bnsum, bnsq, gamma2, beta2, out, N);
}

// Round 18
// 138.562 us; speedup vs baseline: 1.3614x; 1.0363x over previous
//
#include <hip/hip_runtime.h>
#include <hip/hip_bf16.h>

#define NEG_SLOPE 0.2f
#define BN_EPS 1e-5f

typedef _Float16 half8 __attribute__((ext_vector_type(8)));
typedef _Float16 half2v __attribute__((ext_vector_type(2)));
typedef float f32x4 __attribute__((ext_vector_type(4)));

// ---------- fast zero of scratch + output ----------
__global__ void k_zero(uint4* __restrict__ p, int n4, uint4* __restrict__ q, int m4) {
    int i = blockIdx.x * blockDim.x + threadIdx.x;
    if (i < n4) p[i] = (uint4){0u, 0u, 0u, 0u};
    else if (i < n4 + m4) q[i - n4] = (uint4){0u, 0u, 0u, 0u};
}

// ---------- setup: coef (blk0), gbounds (blk1), w2t tile-transpose (blk2..33),
//            edge degree count (blk34..) ----------
__global__ void k_setup(const float* __restrict__ W1, const float* __restrict__ asw,
                        const float* __restrict__ adw, float* __restrict__ coef,
                        const float* __restrict__ W2, _Float16* __restrict__ w2t,
                        const int* __restrict__ batch, int N, int G, int* __restrict__ gb,
                        const int* __restrict__ ei, int E, int E2, int* __restrict__ cnt) {
    __shared__ float tile[32][33];
    int bid = blockIdx.x, t = threadIdx.x;
    if (bid == 0) {
        float w0 = W1[t], w1 = W1[256 + t], as = asw[t], ad = adw[t];
        float v0 = w0 * as, v1 = w1 * as, v2 = w0 * ad, v3 = w1 * ad;
        for (int o = 32; o; o >>= 1) {
            v0 += __shfl_down(v0, o); v1 += __shfl_down(v1, o);
            v2 += __shfl_down(v2, o); v3 += __shfl_down(v3, o);
        }
        if ((t & 63) == 0) {
            int h = t >> 6;
            coef[h * 4 + 0] = v0; coef[h * 4 + 1] = v1;
            coef[h * 4 + 2] = v2; coef[h * 4 + 3] = v3;
        }
    } else if (bid == 1) {
        int g = t;
        if (g <= G) {
            int lo = 0, hi = N;
            while (lo < hi) { int mid = (lo + hi) >> 1; if (batch[mid] < g) lo = mid + 1; else hi = mid; }
            gb[g] = lo;
        }
    } else if (bid < 34) {
        // coalesced 32x32 tile transpose: W2[256][128] -> w2t[128][256]
        int tl = bid - 2;                  // 0..31
        int r0 = (tl >> 2) * 32, c0 = (tl & 3) * 32;
        int tr = t >> 5, tc = t & 31;      // 8 x 32
        #pragma unroll
        for (int i = 0; i < 4; i++)
            tile[tr + 8 * i][tc] = W2[(size_t)(r0 + tr + 8 * i) * 128 + c0 + tc];
        __syncthreads();
        #pragma unroll
        for (int i = 0; i < 4; i++)
            w2t[(size_t)(c0 + tr + 8 * i) * 256 + r0 + tc] = (_Float16)tile[tc][tr + 8 * i];
    } else {
        int i = (bid - 34) * 256 + t;
        if (i < E2) {
            int d = (i < E) ? ei[E + i] : (i - E);
            atomicAdd(&cnt[d], 1);
        }
    }
}

// ---------- hierarchical scan, stage 1 ----------
__global__ void k_scan1(const int* __restrict__ cnt, int* __restrict__ rp,
                        int* __restrict__ bsums, int n) {
    __shared__ int s[1024];
    int i = blockIdx.x * 1024 + threadIdx.x;
    int v = (i < n) ? cnt[i] : 0;
    s[threadIdx.x] = v;
    __syncthreads();
    for (int o = 1; o < 1024; o <<= 1) {
        int t = (threadIdx.x >= o) ? s[threadIdx.x - o] : 0;
        __syncthreads();
        s[threadIdx.x] += t;
        __syncthreads();
    }
    if (i < n) rp[i] = s[threadIdx.x] - v;
    if (threadIdx.x == 1023) bsums[blockIdx.x] = s[1023];
}

// ---------- stage 2: wave-parallel prefix of bsums + offset add (nb <= 64) ----------
__global__ void k_scan2f(int* __restrict__ rp, const int* __restrict__ bsums,
                         int n, int total, int nb) {
    __shared__ int boff;
    if (threadIdx.x < 64) {
        int lane = threadIdx.x;
        int v = (lane < nb) ? bsums[lane] : 0;
        #pragma unroll
        for (int o = 1; o < 64; o <<= 1) {
            int t = __shfl_up(v, o);
            if (lane >= o) v += t;
        }
        int ex = __shfl_up(v, 1);
        if (lane == (int)blockIdx.x) boff = (blockIdx.x == 0) ? 0 : ex;
    }
    __syncthreads();
    int i = blockIdx.x * 1024 + threadIdx.x;
    if (i < n) rp[i] += boff;
    if (blockIdx.x == 0 && threadIdx.x == 0) rp[n] = total;
}

// ---------- scatter: consumes cnt (deg) via atomicSub ----------
__global__ void k_scatter(const int* __restrict__ ei, int E, int E2,
                          const int* __restrict__ rp, int* __restrict__ cnt,
                          int* __restrict__ esrc) {
    int i = blockIdx.x * blockDim.x + threadIdx.x;
    if (i >= E2) return;
    int s, d;
    if (i < E) { s = ei[i]; d = ei[E + i]; } else { s = d = i - E; }
    int old = atomicSub(&cnt[d], 1);
    esrc[rp[d] + old - 1] = s;
}

// ---------- Layer 1 aggregation (rank-2) + fused BN1 stats reduction ----------
__global__ void k_agg1r(const int* __restrict__ rp, const int* __restrict__ esrc,
                        const float* __restrict__ x, const float* __restrict__ coef,
                        float* __restrict__ uv, float* __restrict__ stats, int N) {
    __shared__ float sred[4][20];
    int tid = threadIdx.x, lane = tid & 63, wid = tid >> 6;
    int n = blockIdx.x * blockDim.x + tid;
    float st[20];
    #pragma unroll
    for (int i = 0; i < 20; i++) st[i] = 0.f;

    if (n < N) {
        float c[16];
        #pragma unroll
        for (int i = 0; i < 16; i++) c[i] = coef[i];
        float2 xn = ((const float2*)x)[n];
        float ad[4], den[4], sx[4], sy[4];
        #pragma unroll
        for (int h = 0; h < 4; h++) {
            ad[h] = fmaf(xn.x, c[h * 4 + 2], xn.y * c[h * 4 + 3]);
            den[h] = 0.f; sx[h] = 0.f; sy[h] = 0.f;
        }
        int beg = rp[n], end = rp[n + 1];
        for (int k = beg; k < end; k++) {
            int s = esrc[k];
            float2 xv = ((const float2*)x)[s];
            #pragma unroll
            for (int h = 0; h < 4; h++) {
                float e = fmaf(xv.x, c[h * 4 + 0], xv.y * c[h * 4 + 1]) + ad[h];
                e = e > 0.f ? e : NEG_SLOPE * e;
                float w = __expf(e);
                den[h] += w; sx[h] = fmaf(w, xv.x, sx[h]); sy[h] = fmaf(w, xv.y, sy[h]);
            }
        }
        float* o = uv + (size_t)n * 8;
        #pragma unroll
        for (int h = 0; h < 4; h++) {
            float inv = 1.f / (den[h] + 1e-16f);
            float u = sx[h] * inv, v = sy[h] * inv;
            o[h] = u; o[4 + h] = v;
            st[h] = u; st[4 + h] = v;
            st[8 + h] = u * u; st[12 + h] = v * v; st[16 + h] = u * v;
        }
    }
    #pragma unroll
    for (int i = 0; i < 20; i++)
        for (int o = 32; o; o >>= 1) st[i] += __shfl_down(st[i], o);
    if (lane == 0)
        #pragma unroll
        for (int i = 0; i < 20; i++) sred[wid][i] = st[i];
    __syncthreads();
    if (tid < 20)
        atomicAdd(&stats[tid], sred[0][tid] + sred[1][tid] + sred[2][tid] + sred[3][tid]);
}

// ---------- Layer 2 GEMM via MFMA; 512 threads / 128 rows per block ----------
__global__ __launch_bounds__(512) void k_gemm2(
        const float* __restrict__ uv, const float* __restrict__ stats,
        const float* __restrict__ W1, const float* __restrict__ b1,
        const float* __restrict__ gamma, const float* __restrict__ beta,
        const _Float16* __restrict__ w2t,
        const float* __restrict__ asw, const float* __restrict__ adw,
        _Float16* __restrict__ g2h, float* __restrict__ as2,
        float* __restrict__ ad2, int N) {
    __shared__ _Float16 bs[128][136];
    __shared__ float abcs[768];
    int tid = threadIdx.x, wid = tid >> 6, l = tid & 63;
    int kg = l >> 4, ln = l & 15;
    int n0w = blockIdx.x * 128 + wid * 16;

    if (tid < 256) {
        int j = tid, h = j >> 6;
        float w0 = W1[j], w1 = W1[256 + j], b = b1[j];
        float Su = stats[h], Sv = stats[4 + h], Suu = stats[8 + h],
              Svv = stats[12 + h], Suv = stats[16 + h];
        float fN = (float)N;
        float lin = fmaf(w0, Su, w1 * Sv);
        float mean = lin / fN + b;
        float sq = w0 * w0 * Suu + w1 * w1 * Svv + 2.f * w0 * w1 * Suv + 2.f * b * lin + fN * b * b;
        float var = sq / fN - mean * mean;
        float sc = rsqrtf(var + BN_EPS) * gamma[j];
        float sh = beta[j] - mean * sc;
        abcs[j] = sc * w0;
        abcs[256 + j] = sc * w1;
        abcs[512 + j] = fmaf(sc, b, sh);
    }

    int arow = n0w + ln;
    float uvr[8];
    if (arow < N) {
        const float4* p = (const float4*)(uv + (size_t)arow * 8);
        float4 t0 = p[0], t1 = p[1];
        uvr[0] = t0.x; uvr[1] = t0.y; uvr[2] = t0.z; uvr[3] = t0.w;
        uvr[4] = t1.x; uvr[5] = t1.y; uvr[6] = t1.z; uvr[7] = t1.w;
    } else {
        #pragma unroll
        for (int i = 0; i < 8; i++) uvr[i] = 0.f;
    }

    f32x4 acc[8];
    #pragma unroll
    for (int ct = 0; ct < 8; ct++) acc[ct] = (f32x4){0.f, 0.f, 0.f, 0.f};

    int sc_ = tid >> 2, q = tid & 3;
    for (int s = 0; s < 2; s++) {
        #pragma unroll
        for (int j = 0; j < 4; j++) {
            *(half8*)&bs[sc_][q * 32 + j * 8] =
                *(const half8*)&w2t[(size_t)sc_ * 256 + s * 128 + q * 32 + j * 8];
        }
        __syncthreads();
        #pragma unroll
        for (int kt4 = 0; kt4 < 4; kt4++) {
            int kt = s * 4 + kt4;
            int h = kt >> 1;
            float u = uvr[h], v = uvr[4 + h];
            int kb = kt * 32 + kg * 8;
            float4 A0a = *(const float4*)&abcs[kb],       A0b = *(const float4*)&abcs[kb + 4];
            float4 A1a = *(const float4*)&abcs[256 + kb], A1b = *(const float4*)&abcs[256 + kb + 4];
            float4 A2a = *(const float4*)&abcs[512 + kb], A2b = *(const float4*)&abcs[512 + kb + 4];
            half8 af;
            float y;
            y = fmaf(A0a.x, u, fmaf(A1a.x, v, A2a.x)); af[0] = (_Float16)(y > 0.f ? y : __expf(y) - 1.f);
            y = fmaf(A0a.y, u, fmaf(A1a.y, v, A2a.y)); af[1] = (_Float16)(y > 0.f ? y : __expf(y) - 1.f);
            y = fmaf(A0a.z, u, fmaf(A1a.z, v, A2a.z)); af[2] = (_Float16)(y > 0.f ? y : __expf(y) - 1.f);
            y = fmaf(A0a.w, u, fmaf(A1a.w, v, A2a.w)); af[3] = (_Float16)(y > 0.f ? y : __expf(y) - 1.f);
            y = fmaf(A0b.x, u, fmaf(A1b.x, v, A2b.x)); af[4] = (_Float16)(y > 0.f ? y : __expf(y) - 1.f);
            y = fmaf(A0b.y, u, fmaf(A1b.y, v, A2b.y)); af[5] = (_Float16)(y > 0.f ? y : __expf(y) - 1.f);
            y = fmaf(A0b.z, u, fmaf(A1b.z, v, A2b.z)); af[6] = (_Float16)(y > 0.f ? y : __expf(y) - 1.f);
            y = fmaf(A0b.w, u, fmaf(A1b.w, v, A2b.w)); af[7] = (_Float16)(y > 0.f ? y : __expf(y) - 1.f);
            int klo = kt4 * 32 + kg * 8;
            #pragma unroll
            for (int ct = 0; ct < 8; ct++) {
                half8 bf = *(const half8*)&bs[ct * 16 + ln][klo];
                acc[ct] = __builtin_amdgcn_mfma_f32_16x16x32_f16(af, bf, acc[ct], 0, 0, 0);
            }
        }
        __syncthreads();
    }

    _Float16 (*tbuf)[16][136] = (_Float16 (*)[16][136])&bs[0][0];
    #pragma unroll
    for (int ct = 0; ct < 8; ct++)
        #pragma unroll
        for (int r = 0; r < 4; r++)
            tbuf[wid][kg * 4 + r][ct * 16 + ln] = (_Float16)acc[ct][r];
    __syncthreads();

    int rr = l >> 2, cq = l & 3;
    int node = n0w + rr;
    half8 hv[4];
    #pragma unroll
    for (int j = 0; j < 4; j++) hv[j] = *(const half8*)&tbuf[wid][rr][cq * 32 + j * 8];
    float ps = 0.f, pd = 0.f;
    #pragma unroll
    for (int j = 0; j < 4; j++) {
        int cb = cq * 32 + j * 8;
        float4 s0 = *(const float4*)&asw[cb], s1 = *(const float4*)&asw[cb + 4];
        float4 d0 = *(const float4*)&adw[cb], d1 = *(const float4*)&adw[cb + 4];
        ps = fmaf((float)hv[j][0], s0.x, ps); pd = fmaf((float)hv[j][0], d0.x, pd);
        ps = fmaf((float)hv[j][1], s0.y, ps); pd = fmaf((float)hv[j][1], d0.y, pd);
        ps = fmaf((float)hv[j][2], s0.z, ps); pd = fmaf((float)hv[j][2], d0.z, pd);
        ps = fmaf((float)hv[j][3], s0.w, ps); pd = fmaf((float)hv[j][3], d0.w, pd);
        ps = fmaf((float)hv[j][4], s1.x, ps); pd = fmaf((float)hv[j][4], d1.x, pd);
        ps = fmaf((float)hv[j][5], s1.y, ps); pd = fmaf((float)hv[j][5], d1.y, pd);
        ps = fmaf((float)hv[j][6], s1.z, ps); pd = fmaf((float)hv[j][6], d1.z, pd);
        ps = fmaf((float)hv[j][7], s1.w, ps); pd = fmaf((float)hv[j][7], d1.w, pd);
    }
    ps += __shfl_xor(ps, 1); ps += __shfl_xor(ps, 2);
    pd += __shfl_xor(pd, 1); pd += __shfl_xor(pd, 2);
    if (node < N) {
        #pragma unroll
        for (int j = 0; j < 4; j++)
            *(half8*)&g2h[(size_t)node * 128 + cq * 32 + j * 8] = hv[j];
        if (cq == 0) { as2[node] = ps; ad2[node] = pd; }
    }
}

// ---------- Layer 2 aggregation: wave per node; 2-edge unrolled gathers ----------
__global__ void k_agg2(const int* __restrict__ rp, const int* __restrict__ esrc,
                       const float* __restrict__ as2, const float* __restrict__ ad2,
                       const _Float16* __restrict__ g2h, const float* __restrict__ b2,
                       _Float16* __restrict__ out2h, int N) {
    int wid = threadIdx.x >> 6, lane = threadIdx.x & 63;
    int n = blockIdx.x * 4 + wid;
    if (n >= N) return;
    int beg = rp[n], end = rp[n + 1];
    float ad = ad2[n];
    float ax = 0.f, ay = 0.f, den = 0.f;
    for (int t0 = beg; t0 < end; t0 += 64) {
        int k = t0 + lane;
        int sl = 0; float wl = 0.f;
        if (k < end) {
            sl = esrc[k];
            float e = as2[sl] + ad;
            e = e > 0.f ? e : NEG_SLOPE * e;
            wl = __expf(e);
        }
        int nt = min(64, end - t0);
        int k2 = 0;
        for (; k2 + 1 < nt; k2 += 2) {
            float w0 = __shfl(wl, k2),   w1 = __shfl(wl, k2 + 1);
            int   s0 = __shfl(sl, k2),   s1 = __shfl(sl, k2 + 1);
            half2v g0 = ((const half2v*)g2h)[(size_t)s0 * 64 + lane];
            half2v g1 = ((const half2v*)g2h)[(size_t)s1 * 64 + lane];
            den += w0 + w1;
            ax = fmaf(w0, (float)g0[0], ax); ay = fmaf(w0, (float)g0[1], ay);
            ax = fmaf(w1, (float)g1[0], ax); ay = fmaf(w1, (float)g1[1], ay);
        }
        if (k2 < nt) {
            float w = __shfl(wl, k2);
            int s = __shfl(sl, k2);
            half2v gv = ((const half2v*)g2h)[(size_t)s * 64 + lane];
            den += w;
            ax = fmaf(w, (float)gv[0], ax);
            ay = fmaf(w, (float)gv[1], ay);
        }
    }
    float inv = 1.f / (den + 1e-16f);
    float2 bv = ((const float2*)b2)[lane];
    half2v ov;
    ov[0] = (_Float16)(ax * inv + bv.x);
    ov[1] = (_Float16)(ay * inv + bv.y);
    ((half2v*)out2h)[(size_t)n * 64 + lane] = ov;
}

// ---------- BN2 stats: vectorized half8 loads ----------
__global__ void k_bnstats(const _Float16* __restrict__ v, int N,
                          float* __restrict__ sum, float* __restrict__ sq) {
    __shared__ float wred[4][16][16];
    int t = threadIdx.x;
    int rr = t >> 4, cg = t & 15;
    int rows = (N + gridDim.x - 1) / gridDim.x;
    int r0 = blockIdx.x * rows, r1 = min(N, r0 + rows);
    float s[8], q[8];
    #pragma unroll
    for (int i = 0; i < 8; i++) { s[i] = 0.f; q[i] = 0.f; }
    for (int r = r0 + rr; r < r1; r += 16) {
        half8 hv = *(const half8*)&v[(size_t)r * 128 + cg * 8];
        #pragma unroll
        for (int i = 0; i < 8; i++) {
            float xx = (float)hv[i];
            s[i] += xx; q[i] = fmaf(xx, xx, q[i]);
        }
    }
    #pragma unroll
    for (int i = 0; i < 8; i++) {
        s[i] += __shfl_xor(s[i], 16); s[i] += __shfl_xor(s[i], 32);
        q[i] += __shfl_xor(q[i], 16); q[i] += __shfl_xor(q[i], 32);
    }
    int wave = t >> 6, lane = t & 63;
    if (lane < 16) {
        #pragma unroll
        for (int i = 0; i < 8; i++) {
            wred[wave][lane][i] = s[i];
            wred[wave][lane][8 + i] = q[i];
        }
    }
    __syncthreads();
    {
        int cg2 = t >> 4, e = t & 15;
        float tot = wred[0][cg2][e] + wred[1][cg2][e] + wred[2][cg2][e] + wred[3][cg2][e];
        if (e < 8) atomicAdd(&sum[cg2 * 8 + e], tot);
        else       atomicAdd(&sq[cg2 * 8 + e - 8], tot);
    }
}

// ---------- pooling: one block per (graph, quarter); vectorized ----------
__global__ void k_poolg2(const _Float16* __restrict__ v, const int* __restrict__ gb,
                         const float* __restrict__ bnsum, const float* __restrict__ bnsq,
                         const float* __restrict__ gamma, const float* __restrict__ beta,
                         float* __restrict__ out, int N) {
    __shared__ float wred[4][16][8];
    int t = threadIdx.x;
    int g = blockIdx.x >> 2, qtr = blockIdx.x & 3;
    int rr = t >> 4, cg = t & 15;
    int gs = gb[g], ge = gb[g + 1];
    int len = ge - gs;
    int q0 = gs + (len * qtr) / 4, q1 = gs + (len * (qtr + 1)) / 4;
    float sc[8], sh[8];
    #pragma unroll
    for (int i = 0; i < 8; i++) {
        int j = cg * 8 + i;
        float mu = bnsum[j] / N;
        float var = bnsq[j] / N - mu * mu;
        sc[i] = rsqrtf(var + BN_EPS) * gamma[j];
        sh[i] = beta[j] - mu * sc[i];
    }
    float acc[8];
    #pragma unroll
    for (int i = 0; i < 8; i++) acc[i] = 0.f;
    for (int r = q0 + rr; r < q1; r += 16) {
        half8 hv = *(const half8*)&v[(size_t)r * 128 + cg * 8];
        #pragma unroll
        for (int i = 0; i < 8; i++) {
            float y = fmaf((float)hv[i], sc[i], sh[i]);
            acc[i] += y > 0.f ? y : (__expf(y) - 1.0f);
        }
    }
    #pragma unroll
    for (int i = 0; i < 8; i++) {
        acc[i] += __shfl_xor(acc[i], 16);
        acc[i] += __shfl_xor(acc[i], 32);
    }
    int wave = t >> 6, lane = t & 63;
    if (lane < 16) {
        #pragma unroll
        for (int i = 0; i < 8; i++) wred[wave][lane][i] = acc[i];
    }
    __syncthreads();
    if (t < 128) {
        int cg2 = t >> 3, e = t & 7;
        float tot = wred[0][cg2][e] + wred[1][cg2][e] + wred[2][cg2][e] + wred[3][cg2][e];
        float invc = 1.f / fmaxf((float)len, 1.0f);
        atomicAdd(&out[(size_t)g * 128 + cg2 * 8 + e], tot * invc);
    }
}

extern "C" void kernel_launch(void* const* d_in, const int* in_sizes, int n_in,
                              void* d_out, int out_size, void* d_ws, size_t ws_size,
                              hipStream_t stream) {
    const float* x     = (const float*)d_in[0];
    const int*   ei    = (const int*)d_in[1];
    const int*   batch = (const int*)d_in[2];
    const float* W1    = (const float*)d_in[4];
    const float* asw1  = (const float*)d_in[5];
    const float* adw1  = (const float*)d_in[6];
    const float* b1    = (const float*)d_in[7];
    const float* gamma1= (const float*)d_in[8];
    const float* beta1 = (const float*)d_in[9];
    const float* W2    = (const float*)d_in[10];
    const float* asw2  = (const float*)d_in[11];
    const float* adw2  = (const float*)d_in[12];
    const float* b2    = (const float*)d_in[13];
    const float* gamma2= (const float*)d_in[14];
    const float* beta2 = (const float*)d_in[15];
    float* out = (float*)d_out;

    const int N  = in_sizes[2];
    const int E  = in_sizes[1] / 2;
    const int E2 = E + N;
    const int G  = out_size / 128;

    char* ws = (char*)d_ws;
    size_t off = 0;
    auto A = [&](size_t bytes) { size_t o = off; off += (bytes + 255) & ~(size_t)255; return o; };
    _Float16* g2h  = (_Float16*)(ws + A((size_t)N * 128 * 2));
    _Float16* w2t  = (_Float16*)(ws + A((size_t)128 * 256 * 2));
    _Float16* out2h= (_Float16*)(ws + A((size_t)N * 128 * 2));
    float* uv    = (float*)(ws + A((size_t)N * 8 * 4));
    float* as2   = (float*)(ws + A((size_t)N * 4));
    float* ad2   = (float*)(ws + A((size_t)N * 4));
    float* coef  = (float*)(ws + A(16 * 4));
    int*   gb    = (int*)(ws + A((size_t)(G + 1) * 4));
    int*   rp    = (int*)(ws + A((size_t)(N + 1) * 4));
    int*   esrc  = (int*)(ws + A((size_t)E2 * 4));
    int*   bsums = (int*)(ws + A((size_t)((N + 1023) / 1024) * 4));
    size_t zbytes = ((size_t)N + 20 + 256 + 256) * 4;
    size_t zoff = A(zbytes);
    int*   cnt   = (int*)(ws + zoff);
    float* stats = (float*)(cnt + N);
    float* bnsum = stats + 20;
    float* bnsq  = bnsum + 256;

    const int nb = (N + 1023) / 1024;

    // 1: zero scratch AND the full output buffer
    int n4 = (int)((zbytes + 15) / 16);
    int m4 = (out_size + 3) / 4;
    k_zero<<<(n4 + m4 + 255) / 256, 256, 0, stream>>>((uint4*)(ws + zoff), n4,
                                                      (uint4*)out, m4);

    // 2: setup (coef + gbounds + coalesced w2t transpose + degree count)
    int degBlocks = (E2 + 255) / 256;
    k_setup<<<34 + degBlocks, 256, 0, stream>>>(W1, asw1, adw1, coef, W2, w2t,
                                                batch, N, G, gb, ei, E, E2, cnt);

    // 3-4: hierarchical scan -> rp
    k_scan1<<<nb, 1024, 0, stream>>>(cnt, rp, bsums, N);
    k_scan2f<<<nb, 1024, 0, stream>>>(rp, bsums, N, E2, nb);

    // 5: scatter
    k_scatter<<<degBlocks, 256, 0, stream>>>(ei, E, E2, rp, cnt, esrc);

    // 6: layer-1 rank-2 aggregation + BN1 stats
    k_agg1r<<<(N + 255) / 256, 256, 0, stream>>>(rp, esrc, x, coef, uv, stats, N);

    // 7: layer-2 GEMM via MFMA
    k_gemm2<<<(N + 127) / 128, 512, 0, stream>>>(uv, stats, W1, b1, gamma1, beta1,
                                                 w2t, asw2, adw2, g2h, as2, ad2, N);

    // 8: layer-2 aggregation (2-edge unrolled)
    k_agg2<<<(N + 3) / 4, 256, 0, stream>>>(rp, esrc, as2, ad2, g2h, b2, out2h, N);

    // 9: BN2 stats
    k_bnstats<<<512, 256, 0, stream>>>(out2h, N, bnsum, bnsq);

    // 10: pooling
    k_poolg2<<<G * 4, 256, 0, stream>>>(out2h, gb, bnsum, bnsq, gamma2, beta2, out, N);
}

// Round 19
// 133.162 us; speedup vs baseline: 1.4166x; 1.0406x over previous
//
#include <hip/hip_runtime.h>
#include <hip/hip_bf16.h>

#define NEG_SLOPE 0.2f
#define BN_EPS 1e-5f

typedef _Float16 half8 __attribute__((ext_vector_type(8)));
typedef _Float16 half2v __attribute__((ext_vector_type(2)));
typedef float f32x4 __attribute__((ext_vector_type(4)));

// ---------- fast zero of scratch + output ----------
__global__ void k_zero(uint4* __restrict__ p, int n4, uint4* __restrict__ q, int m4) {
    int i = blockIdx.x * blockDim.x + threadIdx.x;
    if (i < n4) p[i] = (uint4){0u, 0u, 0u, 0u};
    else if (i < n4 + m4) q[i - n4] = (uint4){0u, 0u, 0u, 0u};
}

// ---------- setup: coef (blk0), gbounds (blk1), w2t tile-transpose (blk2..33),
//            edge degree count (blk34..) ----------
__global__ void k_setup(const float* __restrict__ W1, const float* __restrict__ asw,
                        const float* __restrict__ adw, float* __restrict__ coef,
                        const float* __restrict__ W2, _Float16* __restrict__ w2t,
                        const int* __restrict__ batch, int N, int G, int* __restrict__ gb,
                        const int* __restrict__ ei, int E, int E2, int* __restrict__ cnt) {
    __shared__ float tile[32][33];
    int bid = blockIdx.x, t = threadIdx.x;
    if (bid == 0) {
        float w0 = W1[t], w1 = W1[256 + t], as = asw[t], ad = adw[t];
        float v0 = w0 * as, v1 = w1 * as, v2 = w0 * ad, v3 = w1 * ad;
        for (int o = 32; o; o >>= 1) {
            v0 += __shfl_down(v0, o); v1 += __shfl_down(v1, o);
            v2 += __shfl_down(v2, o); v3 += __shfl_down(v3, o);
        }
        if ((t & 63) == 0) {
            int h = t >> 6;
            coef[h * 4 + 0] = v0; coef[h * 4 + 1] = v1;
            coef[h * 4 + 2] = v2; coef[h * 4 + 3] = v3;
        }
    } else if (bid == 1) {
        int g = t;
        if (g <= G) {
            int lo = 0, hi = N;
            while (lo < hi) { int mid = (lo + hi) >> 1; if (batch[mid] < g) lo = mid + 1; else hi = mid; }
            gb[g] = lo;
        }
    } else if (bid < 34) {
        int tl = bid - 2;
        int r0 = (tl >> 2) * 32, c0 = (tl & 3) * 32;
        int tr = t >> 5, tc = t & 31;
        #pragma unroll
        for (int i = 0; i < 4; i++)
            tile[tr + 8 * i][tc] = W2[(size_t)(r0 + tr + 8 * i) * 128 + c0 + tc];
        __syncthreads();
        #pragma unroll
        for (int i = 0; i < 4; i++)
            w2t[(size_t)(c0 + tr + 8 * i) * 256 + r0 + tc] = (_Float16)tile[tc][tr + 8 * i];
    } else {
        int i = (bid - 34) * 256 + t;
        if (i < E2) {
            int d = (i < E) ? ei[E + i] : (i - E);
            atomicAdd(&cnt[d], 1);
        }
    }
}

// ---------- hierarchical scan, stage 1 ----------
__global__ void k_scan1(const int* __restrict__ cnt, int* __restrict__ rp,
                        int* __restrict__ bsums, int n) {
    __shared__ int s[1024];
    int i = blockIdx.x * 1024 + threadIdx.x;
    int v = (i < n) ? cnt[i] : 0;
    s[threadIdx.x] = v;
    __syncthreads();
    for (int o = 1; o < 1024; o <<= 1) {
        int t = (threadIdx.x >= o) ? s[threadIdx.x - o] : 0;
        __syncthreads();
        s[threadIdx.x] += t;
        __syncthreads();
    }
    if (i < n) rp[i] = s[threadIdx.x] - v;
    if (threadIdx.x == 1023) bsums[blockIdx.x] = s[1023];
}

// ---------- stage 2: wave-parallel prefix of bsums + offset add ----------
__global__ void k_scan2f(int* __restrict__ rp, const int* __restrict__ bsums,
                         int n, int total, int nb) {
    __shared__ int boff;
    if (threadIdx.x < 64) {
        int lane = threadIdx.x;
        int v = (lane < nb) ? bsums[lane] : 0;
        #pragma unroll
        for (int o = 1; o < 64; o <<= 1) {
            int t = __shfl_up(v, o);
            if (lane >= o) v += t;
        }
        int ex = __shfl_up(v, 1);
        if (lane == (int)blockIdx.x) boff = (blockIdx.x == 0) ? 0 : ex;
    }
    __syncthreads();
    int i = blockIdx.x * 1024 + threadIdx.x;
    if (i < n) rp[i] += boff;
    if (blockIdx.x == 0 && threadIdx.x == 0) rp[n] = total;
}

// ---------- scatter: consumes cnt (deg) via atomicSub ----------
__global__ void k_scatter(const int* __restrict__ ei, int E, int E2,
                          const int* __restrict__ rp, int* __restrict__ cnt,
                          int* __restrict__ esrc) {
    int i = blockIdx.x * blockDim.x + threadIdx.x;
    if (i >= E2) return;
    int s, d;
    if (i < E) { s = ei[i]; d = ei[E + i]; } else { s = d = i - E; }
    int old = atomicSub(&cnt[d], 1);
    esrc[rp[d] + old - 1] = s;
}

// ---------- Layer 1 aggregation (rank-2), 2-edge unrolled + BN1 stats ----------
__global__ void k_agg1r(const int* __restrict__ rp, const int* __restrict__ esrc,
                        const float* __restrict__ x, const float* __restrict__ coef,
                        float* __restrict__ uv, float* __restrict__ stats, int N) {
    __shared__ float sred[4][20];
    int tid = threadIdx.x, lane = tid & 63, wid = tid >> 6;
    int n = blockIdx.x * blockDim.x + tid;
    float st[20];
    #pragma unroll
    for (int i = 0; i < 20; i++) st[i] = 0.f;

    if (n < N) {
        float c[16];
        #pragma unroll
        for (int i = 0; i < 16; i++) c[i] = coef[i];
        float2 xn = ((const float2*)x)[n];
        float ad[4], den[4], sx[4], sy[4];
        #pragma unroll
        for (int h = 0; h < 4; h++) {
            ad[h] = fmaf(xn.x, c[h * 4 + 2], xn.y * c[h * 4 + 3]);
            den[h] = 0.f; sx[h] = 0.f; sy[h] = 0.f;
        }
        int beg = rp[n], end = rp[n + 1];
        int k = beg;
        for (; k + 1 < end; k += 2) {
            int s0 = esrc[k], s1 = esrc[k + 1];
            float2 xv0 = ((const float2*)x)[s0];
            float2 xv1 = ((const float2*)x)[s1];
            #pragma unroll
            for (int h = 0; h < 4; h++) {
                float e0 = fmaf(xv0.x, c[h * 4 + 0], xv0.y * c[h * 4 + 1]) + ad[h];
                float e1 = fmaf(xv1.x, c[h * 4 + 0], xv1.y * c[h * 4 + 1]) + ad[h];
                e0 = e0 > 0.f ? e0 : NEG_SLOPE * e0;
                e1 = e1 > 0.f ? e1 : NEG_SLOPE * e1;
                float w0 = __expf(e0), w1 = __expf(e1);
                den[h] += w0 + w1;
                sx[h] = fmaf(w0, xv0.x, sx[h]); sy[h] = fmaf(w0, xv0.y, sy[h]);
                sx[h] = fmaf(w1, xv1.x, sx[h]); sy[h] = fmaf(w1, xv1.y, sy[h]);
            }
        }
        if (k < end) {
            int s = esrc[k];
            float2 xv = ((const float2*)x)[s];
            #pragma unroll
            for (int h = 0; h < 4; h++) {
                float e = fmaf(xv.x, c[h * 4 + 0], xv.y * c[h * 4 + 1]) + ad[h];
                e = e > 0.f ? e : NEG_SLOPE * e;
                float w = __expf(e);
                den[h] += w; sx[h] = fmaf(w, xv.x, sx[h]); sy[h] = fmaf(w, xv.y, sy[h]);
            }
        }
        float* o = uv + (size_t)n * 8;
        #pragma unroll
        for (int h = 0; h < 4; h++) {
            float inv = 1.f / (den[h] + 1e-16f);
            float u = sx[h] * inv, v = sy[h] * inv;
            o[h] = u; o[4 + h] = v;
            st[h] = u; st[4 + h] = v;
            st[8 + h] = u * u; st[12 + h] = v * v; st[16 + h] = u * v;
        }
    }
    #pragma unroll
    for (int i = 0; i < 20; i++)
        for (int o = 32; o; o >>= 1) st[i] += __shfl_down(st[i], o);
    if (lane == 0)
        #pragma unroll
        for (int i = 0; i < 20; i++) sred[wid][i] = st[i];
    __syncthreads();
    if (tid < 20)
        atomicAdd(&stats[tid], sred[0][tid] + sred[1][tid] + sred[2][tid] + sred[3][tid]);
}

// ---------- Layer 2 GEMM via MFMA; 512 threads / 128 rows per block ----------
__global__ __launch_bounds__(512) void k_gemm2(
        const float* __restrict__ uv, const float* __restrict__ stats,
        const float* __restrict__ W1, const float* __restrict__ b1,
        const float* __restrict__ gamma, const float* __restrict__ beta,
        const _Float16* __restrict__ w2t,
        const float* __restrict__ asw, const float* __restrict__ adw,
        _Float16* __restrict__ g2h, float* __restrict__ as2,
        float* __restrict__ ad2, int N) {
    __shared__ _Float16 bs[128][136];
    __shared__ float abcs[768];
    int tid = threadIdx.x, wid = tid >> 6, l = tid & 63;
    int kg = l >> 4, ln = l & 15;
    int n0w = blockIdx.x * 128 + wid * 16;

    if (tid < 256) {
        int j = tid, h = j >> 6;
        float w0 = W1[j], w1 = W1[256 + j], b = b1[j];
        float Su = stats[h], Sv = stats[4 + h], Suu = stats[8 + h],
              Svv = stats[12 + h], Suv = stats[16 + h];
        float fN = (float)N;
        float lin = fmaf(w0, Su, w1 * Sv);
        float mean = lin / fN + b;
        float sq = w0 * w0 * Suu + w1 * w1 * Svv + 2.f * w0 * w1 * Suv + 2.f * b * lin + fN * b * b;
        float var = sq / fN - mean * mean;
        float sc = rsqrtf(var + BN_EPS) * gamma[j];
        float sh = beta[j] - mean * sc;
        abcs[j] = sc * w0;
        abcs[256 + j] = sc * w1;
        abcs[512 + j] = fmaf(sc, b, sh);
    }

    int arow = n0w + ln;
    float uvr[8];
    if (arow < N) {
        const float4* p = (const float4*)(uv + (size_t)arow * 8);
        float4 t0 = p[0], t1 = p[1];
        uvr[0] = t0.x; uvr[1] = t0.y; uvr[2] = t0.z; uvr[3] = t0.w;
        uvr[4] = t1.x; uvr[5] = t1.y; uvr[6] = t1.z; uvr[7] = t1.w;
    } else {
        #pragma unroll
        for (int i = 0; i < 8; i++) uvr[i] = 0.f;
    }

    f32x4 acc[8];
    #pragma unroll
    for (int ct = 0; ct < 8; ct++) acc[ct] = (f32x4){0.f, 0.f, 0.f, 0.f};

    int sc_ = tid >> 2, q = tid & 3;
    for (int s = 0; s < 2; s++) {
        #pragma unroll
        for (int j = 0; j < 4; j++) {
            *(half8*)&bs[sc_][q * 32 + j * 8] =
                *(const half8*)&w2t[(size_t)sc_ * 256 + s * 128 + q * 32 + j * 8];
        }
        __syncthreads();
        #pragma unroll
        for (int kt4 = 0; kt4 < 4; kt4++) {
            int kt = s * 4 + kt4;
            int h = kt >> 1;
            float u = uvr[h], v = uvr[4 + h];
            int kb = kt * 32 + kg * 8;
            float4 A0a = *(const float4*)&abcs[kb],       A0b = *(const float4*)&abcs[kb + 4];
            float4 A1a = *(const float4*)&abcs[256 + kb], A1b = *(const float4*)&abcs[256 + kb + 4];
            float4 A2a = *(const float4*)&abcs[512 + kb], A2b = *(const float4*)&abcs[512 + kb + 4];
            half8 af;
            float y;
            y = fmaf(A0a.x, u, fmaf(A1a.x, v, A2a.x)); af[0] = (_Float16)(y > 0.f ? y : __expf(y) - 1.f);
            y = fmaf(A0a.y, u, fmaf(A1a.y, v, A2a.y)); af[1] = (_Float16)(y > 0.f ? y : __expf(y) - 1.f);
            y = fmaf(A0a.z, u, fmaf(A1a.z, v, A2a.z)); af[2] = (_Float16)(y > 0.f ? y : __expf(y) - 1.f);
            y = fmaf(A0a.w, u, fmaf(A1a.w, v, A2a.w)); af[3] = (_Float16)(y > 0.f ? y : __expf(y) - 1.f);
            y = fmaf(A0b.x, u, fmaf(A1b.x, v, A2b.x)); af[4] = (_Float16)(y > 0.f ? y : __expf(y) - 1.f);
            y = fmaf(A0b.y, u, fmaf(A1b.y, v, A2b.y)); af[5] = (_Float16)(y > 0.f ? y : __expf(y) - 1.f);
            y = fmaf(A0b.z, u, fmaf(A1b.z, v, A2b.z)); af[6] = (_Float16)(y > 0.f ? y : __expf(y) - 1.f);
            y = fmaf(A0b.w, u, fmaf(A1b.w, v, A2b.w)); af[7] = (_Float16)(y > 0.f ? y : __expf(y) - 1.f);
            int klo = kt4 * 32 + kg * 8;
            #pragma unroll
            for (int ct = 0; ct < 8; ct++) {
                half8 bf = *(const half8*)&bs[ct * 16 + ln][klo];
                acc[ct] = __builtin_amdgcn_mfma_f32_16x16x32_f16(af, bf, acc[ct], 0, 0, 0);
            }
        }
        __syncthreads();
    }

    _Float16 (*tbuf)[16][136] = (_Float16 (*)[16][136])&bs[0][0];
    #pragma unroll
    for (int ct = 0; ct < 8; ct++)
        #pragma unroll
        for (int r = 0; r < 4; r++)
            tbuf[wid][kg * 4 + r][ct * 16 + ln] = (_Float16)acc[ct][r];
    __syncthreads();

    int rr = l >> 2, cq = l & 3;
    int node = n0w + rr;
    half8 hv[4];
    #pragma unroll
    for (int j = 0; j < 4; j++) hv[j] = *(const half8*)&tbuf[wid][rr][cq * 32 + j * 8];
    float ps = 0.f, pd = 0.f;
    #pragma unroll
    for (int j = 0; j < 4; j++) {
        int cb = cq * 32 + j * 8;
        float4 s0 = *(const float4*)&asw[cb], s1 = *(const float4*)&asw[cb + 4];
        float4 d0 = *(const float4*)&adw[cb], d1 = *(const float4*)&adw[cb + 4];
        ps = fmaf((float)hv[j][0], s0.x, ps); pd = fmaf((float)hv[j][0], d0.x, pd);
        ps = fmaf((float)hv[j][1], s0.y, ps); pd = fmaf((float)hv[j][1], d0.y, pd);
        ps = fmaf((float)hv[j][2], s0.z, ps); pd = fmaf((float)hv[j][2], d0.z, pd);
        ps = fmaf((float)hv[j][3], s0.w, ps); pd = fmaf((float)hv[j][3], d0.w, pd);
        ps = fmaf((float)hv[j][4], s1.x, ps); pd = fmaf((float)hv[j][4], d1.x, pd);
        ps = fmaf((float)hv[j][5], s1.y, ps); pd = fmaf((float)hv[j][5], d1.y, pd);
        ps = fmaf((float)hv[j][6], s1.z, ps); pd = fmaf((float)hv[j][6], d1.z, pd);
        ps = fmaf((float)hv[j][7], s1.w, ps); pd = fmaf((float)hv[j][7], d1.w, pd);
    }
    ps += __shfl_xor(ps, 1); ps += __shfl_xor(ps, 2);
    pd += __shfl_xor(pd, 1); pd += __shfl_xor(pd, 2);
    if (node < N) {
        #pragma unroll
        for (int j = 0; j < 4; j++)
            *(half8*)&g2h[(size_t)node * 128 + cq * 32 + j * 8] = hv[j];
        if (cq == 0) { as2[node] = ps; ad2[node] = pd; }
    }
}

// ---------- Layer 2 aggregation: wave per node; 4-edge unrolled gathers ----------
__global__ void k_agg2(const int* __restrict__ rp, const int* __restrict__ esrc,
                       const float* __restrict__ as2, const float* __restrict__ ad2,
                       const _Float16* __restrict__ g2h, const float* __restrict__ b2,
                       _Float16* __restrict__ out2h, int N) {
    int wid = threadIdx.x >> 6, lane = threadIdx.x & 63;
    int n = blockIdx.x * 4 + wid;
    if (n >= N) return;
    int beg = rp[n], end = rp[n + 1];
    float ad = ad2[n];
    float ax = 0.f, ay = 0.f, den = 0.f;
    for (int t0 = beg; t0 < end; t0 += 64) {
        int k = t0 + lane;
        int sl = 0; float wl = 0.f;
        if (k < end) {
            sl = esrc[k];
            float e = as2[sl] + ad;
            e = e > 0.f ? e : NEG_SLOPE * e;
            wl = __expf(e);
        }
        int nt = min(64, end - t0);
        int k2 = 0;
        for (; k2 + 3 < nt; k2 += 4) {
            float w0 = __shfl(wl, k2),     w1 = __shfl(wl, k2 + 1);
            float w2 = __shfl(wl, k2 + 2), w3 = __shfl(wl, k2 + 3);
            int   s0 = __shfl(sl, k2),     s1 = __shfl(sl, k2 + 1);
            int   s2 = __shfl(sl, k2 + 2), s3 = __shfl(sl, k2 + 3);
            half2v g0 = ((const half2v*)g2h)[(size_t)s0 * 64 + lane];
            half2v g1 = ((const half2v*)g2h)[(size_t)s1 * 64 + lane];
            half2v g2 = ((const half2v*)g2h)[(size_t)s2 * 64 + lane];
            half2v g3 = ((const half2v*)g2h)[(size_t)s3 * 64 + lane];
            den += (w0 + w1) + (w2 + w3);
            ax = fmaf(w0, (float)g0[0], ax); ay = fmaf(w0, (float)g0[1], ay);
            ax = fmaf(w1, (float)g1[0], ax); ay = fmaf(w1, (float)g1[1], ay);
            ax = fmaf(w2, (float)g2[0], ax); ay = fmaf(w2, (float)g2[1], ay);
            ax = fmaf(w3, (float)g3[0], ax); ay = fmaf(w3, (float)g3[1], ay);
        }
        for (; k2 < nt; k2++) {
            float w = __shfl(wl, k2);
            int s = __shfl(sl, k2);
            half2v gv = ((const half2v*)g2h)[(size_t)s * 64 + lane];
            den += w;
            ax = fmaf(w, (float)gv[0], ax);
            ay = fmaf(w, (float)gv[1], ay);
        }
    }
    float inv = 1.f / (den + 1e-16f);
    float2 bv = ((const float2*)b2)[lane];
    half2v ov;
    ov[0] = (_Float16)(ax * inv + bv.x);
    ov[1] = (_Float16)(ay * inv + bv.y);
    ((half2v*)out2h)[(size_t)n * 64 + lane] = ov;
}

// ---------- BN2 stats: vectorized half8 loads ----------
__global__ void k_bnstats(const _Float16* __restrict__ v, int N,
                          float* __restrict__ sum, float* __restrict__ sq) {
    __shared__ float wred[4][16][16];
    int t = threadIdx.x;
    int rr = t >> 4, cg = t & 15;
    int rows = (N + gridDim.x - 1) / gridDim.x;
    int r0 = blockIdx.x * rows, r1 = min(N, r0 + rows);
    float s[8], q[8];
    #pragma unroll
    for (int i = 0; i < 8; i++) { s[i] = 0.f; q[i] = 0.f; }
    for (int r = r0 + rr; r < r1; r += 16) {
        half8 hv = *(const half8*)&v[(size_t)r * 128 + cg * 8];
        #pragma unroll
        for (int i = 0; i < 8; i++) {
            float xx = (float)hv[i];
            s[i] += xx; q[i] = fmaf(xx, xx, q[i]);
        }
    }
    #pragma unroll
    for (int i = 0; i < 8; i++) {
        s[i] += __shfl_xor(s[i], 16); s[i] += __shfl_xor(s[i], 32);
        q[i] += __shfl_xor(q[i], 16); q[i] += __shfl_xor(q[i], 32);
    }
    int wave = t >> 6, lane = t & 63;
    if (lane < 16) {
        #pragma unroll
        for (int i = 0; i < 8; i++) {
            wred[wave][lane][i] = s[i];
            wred[wave][lane][8 + i] = q[i];
        }
    }
    __syncthreads();
    {
        int cg2 = t >> 4, e = t & 15;
        float tot = wred[0][cg2][e] + wred[1][cg2][e] + wred[2][cg2][e] + wred[3][cg2][e];
        if (e < 8) atomicAdd(&sum[cg2 * 8 + e], tot);
        else       atomicAdd(&sq[cg2 * 8 + e - 8], tot);
    }
}

// ---------- pooling: one block per (graph, quarter); vectorized ----------
__global__ void k_poolg2(const _Float16* __restrict__ v, const int* __restrict__ gb,
                         const float* __restrict__ bnsum, const float* __restrict__ bnsq,
                         const float* __restrict__ gamma, const float* __restrict__ beta,
                         float* __restrict__ out, int N) {
    __shared__ float wred[4][16][8];
    int t = threadIdx.x;
    int g = blockIdx.x >> 2, qtr = blockIdx.x & 3;
    int rr = t >> 4, cg = t & 15;
    int gs = gb[g], ge = gb[g + 1];
    int len = ge - gs;
    int q0 = gs + (len * qtr) / 4, q1 = gs + (len * (qtr + 1)) / 4;
    float sc[8], sh[8];
    #pragma unroll
    for (int i = 0; i < 8; i++) {
        int j = cg * 8 + i;
        float mu = bnsum[j] / N;
        float var = bnsq[j] / N - mu * mu;
        sc[i] = rsqrtf(var + BN_EPS) * gamma[j];
        sh[i] = beta[j] - mu * sc[i];
    }
    float acc[8];
    #pragma unroll
    for (int i = 0; i < 8; i++) acc[i] = 0.f;
    for (int r = q0 + rr; r < q1; r += 16) {
        half8 hv = *(const half8*)&v[(size_t)r * 128 + cg * 8];
        #pragma unroll
        for (int i = 0; i < 8; i++) {
            float y = fmaf((float)hv[i], sc[i], sh[i]);
            acc[i] += y > 0.f ? y : (__expf(y) - 1.0f);
        }
    }
    #pragma unroll
    for (int i = 0; i < 8; i++) {
        acc[i] += __shfl_xor(acc[i], 16);
        acc[i] += __shfl_xor(acc[i], 32);
    }
    int wave = t >> 6, lane = t & 63;
    if (lane < 16) {
        #pragma unroll
        for (int i = 0; i < 8; i++) wred[wave][lane][i] = acc[i];
    }
    __syncthreads();
    if (t < 128) {
        int cg2 = t >> 3, e = t & 7;
        float tot = wred[0][cg2][e] + wred[1][cg2][e] + wred[2][cg2][e] + wred[3][cg2][e];
        float invc = 1.f / fmaxf((float)len, 1.0f);
        atomicAdd(&out[(size_t)g * 128 + cg2 * 8 + e], tot * invc);
    }
}

extern "C" void kernel_launch(void* const* d_in, const int* in_sizes, int n_in,
                              void* d_out, int out_size, void* d_ws, size_t ws_size,
                              hipStream_t stream) {
    const float* x     = (const float*)d_in[0];
    const int*   ei    = (const int*)d_in[1];
    const int*   batch = (const int*)d_in[2];
    const float* W1    = (const float*)d_in[4];
    const float* asw1  = (const float*)d_in[5];
    const float* adw1  = (const float*)d_in[6];
    const float* b1    = (const float*)d_in[7];
    const float* gamma1= (const float*)d_in[8];
    const float* beta1 = (const float*)d_in[9];
    const float* W2    = (const float*)d_in[10];
    const float* asw2  = (const float*)d_in[11];
    const float* adw2  = (const float*)d_in[12];
    const float* b2    = (const float*)d_in[13];
    const float* gamma2= (const float*)d_in[14];
    const float* beta2 = (const float*)d_in[15];
    float* out = (float*)d_out;

    const int N  = in_sizes[2];
    const int E  = in_sizes[1] / 2;
    const int E2 = E + N;
    const int G  = out_size / 128;

    char* ws = (char*)d_ws;
    size_t off = 0;
    auto A = [&](size_t bytes) { size_t o = off; off += (bytes + 255) & ~(size_t)255; return o; };
    _Float16* g2h  = (_Float16*)(ws + A((size_t)N * 128 * 2));
    _Float16* w2t  = (_Float16*)(ws + A((size_t)128 * 256 * 2));
    _Float16* out2h= (_Float16*)(ws + A((size_t)N * 128 * 2));
    float* uv    = (float*)(ws + A((size_t)N * 8 * 4));
    float* as2   = (float*)(ws + A((size_t)N * 4));
    float* ad2   = (float*)(ws + A((size_t)N * 4));
    float* coef  = (float*)(ws + A(16 * 4));
    int*   gb    = (int*)(ws + A((size_t)(G + 1) * 4));
    int*   rp    = (int*)(ws + A((size_t)(N + 1) * 4));
    int*   esrc  = (int*)(ws + A((size_t)E2 * 4));
    int*   bsums = (int*)(ws + A((size_t)((N + 1023) / 1024) * 4));
    size_t zbytes = ((size_t)N + 20 + 256 + 256) * 4;
    size_t zoff = A(zbytes);
    int*   cnt   = (int*)(ws + zoff);
    float* stats = (float*)(cnt + N);
    float* bnsum = stats + 20;
    float* bnsq  = bnsum + 256;

    const int nb = (N + 1023) / 1024;

    // 1: zero scratch AND the full output buffer
    int n4 = (int)((zbytes + 15) / 16);
    int m4 = (out_size + 3) / 4;
    k_zero<<<(n4 + m4 + 255) / 256, 256, 0, stream>>>((uint4*)(ws + zoff), n4,
                                                      (uint4*)out, m4);

    // 2: setup
    int degBlocks = (E2 + 255) / 256;
    k_setup<<<34 + degBlocks, 256, 0, stream>>>(W1, asw1, adw1, coef, W2, w2t,
                                                batch, N, G, gb, ei, E, E2, cnt);

    // 3-4: hierarchical scan -> rp
    k_scan1<<<nb, 1024, 0, stream>>>(cnt, rp, bsums, N);
    k_scan2f<<<nb, 1024, 0, stream>>>(rp, bsums, N, E2, nb);

    // 5: scatter
    k_scatter<<<degBlocks, 256, 0, stream>>>(ei, E, E2, rp, cnt, esrc);

    // 6: layer-1 rank-2 aggregation (2-edge unrolled) + BN1 stats
    k_agg1r<<<(N + 255) / 256, 256, 0, stream>>>(rp, esrc, x, coef, uv, stats, N);

    // 7: layer-2 GEMM via MFMA
    k_gemm2<<<(N + 127) / 128, 512, 0, stream>>>(uv, stats, W1, b1, gamma1, beta1,
                                                 w2t, asw2, adw2, g2h, as2, ad2, N);

    // 8: layer-2 aggregation (4-edge unrolled)
    k_agg2<<<(N + 3) / 4, 256, 0, stream>>>(rp, esrc, as2, ad2, g2h, b2, out2h, N);

    // 9: BN2 stats
    k_bnstats<<<512, 256, 0, stream>>>(out2h, N, bnsum, bnsq);

    // 10: pooling
    k_poolg2<<<G * 4, 256, 0, stream>>>(out2h, gb, bnsum, bnsq, gamma2, beta2, out, N);
}

// Round 20
// 128.200 us; speedup vs baseline: 1.4714x; 1.0387x over previous
//
#include <hip/hip_runtime.h>
#include <hip/hip_bf16.h>

#define NEG_SLOPE 0.2f
#define BN_EPS 1e-5f

typedef _Float16 half8 __attribute__((ext_vector_type(8)));
typedef _Float16 half4v __attribute__((ext_vector_type(4)));
typedef _Float16 half2v __attribute__((ext_vector_type(2)));
typedef float f32x4 __attribute__((ext_vector_type(4)));

// ---------- fast zero of scratch + output ----------
__global__ void k_zero(uint4* __restrict__ p, int n4, uint4* __restrict__ q, int m4) {
    int i = blockIdx.x * blockDim.x + threadIdx.x;
    if (i < n4) p[i] = (uint4){0u, 0u, 0u, 0u};
    else if (i < n4 + m4) q[i - n4] = (uint4){0u, 0u, 0u, 0u};
}

// ---------- setup: coef (blk0), gbounds (blk1), w2t tile-transpose (blk2..33),
//            edge degree count (blk34..) ----------
__global__ void k_setup(const float* __restrict__ W1, const float* __restrict__ asw,
                        const float* __restrict__ adw, float* __restrict__ coef,
                        const float* __restrict__ W2, _Float16* __restrict__ w2t,
                        const int* __restrict__ batch, int N, int G, int* __restrict__ gb,
                        const int* __restrict__ ei, int E, int E2, int* __restrict__ cnt) {
    __shared__ float tile[32][33];
    int bid = blockIdx.x, t = threadIdx.x;
    if (bid == 0) {
        float w0 = W1[t], w1 = W1[256 + t], as = asw[t], ad = adw[t];
        float v0 = w0 * as, v1 = w1 * as, v2 = w0 * ad, v3 = w1 * ad;
        for (int o = 32; o; o >>= 1) {
            v0 += __shfl_down(v0, o); v1 += __shfl_down(v1, o);
            v2 += __shfl_down(v2, o); v3 += __shfl_down(v3, o);
        }
        if ((t & 63) == 0) {
            int h = t >> 6;
            coef[h * 4 + 0] = v0; coef[h * 4 + 1] = v1;
            coef[h * 4 + 2] = v2; coef[h * 4 + 3] = v3;
        }
    } else if (bid == 1) {
        int g = t;
        if (g <= G) {
            int lo = 0, hi = N;
            while (lo < hi) { int mid = (lo + hi) >> 1; if (batch[mid] < g) lo = mid + 1; else hi = mid; }
            gb[g] = lo;
        }
    } else if (bid < 34) {
        int tl = bid - 2;
        int r0 = (tl >> 2) * 32, c0 = (tl & 3) * 32;
        int tr = t >> 5, tc = t & 31;
        #pragma unroll
        for (int i = 0; i < 4; i++)
            tile[tr + 8 * i][tc] = W2[(size_t)(r0 + tr + 8 * i) * 128 + c0 + tc];
        __syncthreads();
        #pragma unroll
        for (int i = 0; i < 4; i++)
            w2t[(size_t)(c0 + tr + 8 * i) * 256 + r0 + tc] = (_Float16)tile[tc][tr + 8 * i];
    } else {
        int i = (bid - 34) * 256 + t;
        if (i < E2) {
            int d = (i < E) ? ei[E + i] : (i - E);
            atomicAdd(&cnt[d], 1);
        }
    }
}

// ---------- hierarchical scan, stage 1 ----------
__global__ void k_scan1(const int* __restrict__ cnt, int* __restrict__ rp,
                        int* __restrict__ bsums, int n) {
    __shared__ int s[1024];
    int i = blockIdx.x * 1024 + threadIdx.x;
    int v = (i < n) ? cnt[i] : 0;
    s[threadIdx.x] = v;
    __syncthreads();
    for (int o = 1; o < 1024; o <<= 1) {
        int t = (threadIdx.x >= o) ? s[threadIdx.x - o] : 0;
        __syncthreads();
        s[threadIdx.x] += t;
        __syncthreads();
    }
    if (i < n) rp[i] = s[threadIdx.x] - v;
    if (threadIdx.x == 1023) bsums[blockIdx.x] = s[1023];
}

// ---------- stage 2: wave-parallel prefix of bsums + offset add ----------
__global__ void k_scan2f(int* __restrict__ rp, const int* __restrict__ bsums,
                         int n, int total, int nb) {
    __shared__ int boff;
    if (threadIdx.x < 64) {
        int lane = threadIdx.x;
        int v = (lane < nb) ? bsums[lane] : 0;
        #pragma unroll
        for (int o = 1; o < 64; o <<= 1) {
            int t = __shfl_up(v, o);
            if (lane >= o) v += t;
        }
        int ex = __shfl_up(v, 1);
        if (lane == (int)blockIdx.x) boff = (blockIdx.x == 0) ? 0 : ex;
    }
    __syncthreads();
    int i = blockIdx.x * 1024 + threadIdx.x;
    if (i < n) rp[i] += boff;
    if (blockIdx.x == 0 && threadIdx.x == 0) rp[n] = total;
}

// ---------- scatter: consumes cnt (deg) via atomicSub ----------
__global__ void k_scatter(const int* __restrict__ ei, int E, int E2,
                          const int* __restrict__ rp, int* __restrict__ cnt,
                          int* __restrict__ esrc) {
    int i = blockIdx.x * blockDim.x + threadIdx.x;
    if (i >= E2) return;
    int s, d;
    if (i < E) { s = ei[i]; d = ei[E + i]; } else { s = d = i - E; }
    int old = atomicSub(&cnt[d], 1);
    esrc[rp[d] + old - 1] = s;
}

// ---------- Layer 1 aggregation (rank-2), 2-edge unrolled + BN1 stats ----------
__global__ void k_agg1r(const int* __restrict__ rp, const int* __restrict__ esrc,
                        const float* __restrict__ x, const float* __restrict__ coef,
                        float* __restrict__ uv, float* __restrict__ stats, int N) {
    __shared__ float sred[4][20];
    int tid = threadIdx.x, lane = tid & 63, wid = tid >> 6;
    int n = blockIdx.x * blockDim.x + tid;
    float st[20];
    #pragma unroll
    for (int i = 0; i < 20; i++) st[i] = 0.f;

    if (n < N) {
        float c[16];
        #pragma unroll
        for (int i = 0; i < 16; i++) c[i] = coef[i];
        float2 xn = ((const float2*)x)[n];
        float ad[4], den[4], sx[4], sy[4];
        #pragma unroll
        for (int h = 0; h < 4; h++) {
            ad[h] = fmaf(xn.x, c[h * 4 + 2], xn.y * c[h * 4 + 3]);
            den[h] = 0.f; sx[h] = 0.f; sy[h] = 0.f;
        }
        int beg = rp[n], end = rp[n + 1];
        int k = beg;
        for (; k + 1 < end; k += 2) {
            int s0 = esrc[k], s1 = esrc[k + 1];
            float2 xv0 = ((const float2*)x)[s0];
            float2 xv1 = ((const float2*)x)[s1];
            #pragma unroll
            for (int h = 0; h < 4; h++) {
                float e0 = fmaf(xv0.x, c[h * 4 + 0], xv0.y * c[h * 4 + 1]) + ad[h];
                float e1 = fmaf(xv1.x, c[h * 4 + 0], xv1.y * c[h * 4 + 1]) + ad[h];
                e0 = e0 > 0.f ? e0 : NEG_SLOPE * e0;
                e1 = e1 > 0.f ? e1 : NEG_SLOPE * e1;
                float w0 = __expf(e0), w1 = __expf(e1);
                den[h] += w0 + w1;
                sx[h] = fmaf(w0, xv0.x, sx[h]); sy[h] = fmaf(w0, xv0.y, sy[h]);
                sx[h] = fmaf(w1, xv1.x, sx[h]); sy[h] = fmaf(w1, xv1.y, sy[h]);
            }
        }
        if (k < end) {
            int s = esrc[k];
            float2 xv = ((const float2*)x)[s];
            #pragma unroll
            for (int h = 0; h < 4; h++) {
                float e = fmaf(xv.x, c[h * 4 + 0], xv.y * c[h * 4 + 1]) + ad[h];
                e = e > 0.f ? e : NEG_SLOPE * e;
                float w = __expf(e);
                den[h] += w; sx[h] = fmaf(w, xv.x, sx[h]); sy[h] = fmaf(w, xv.y, sy[h]);
            }
        }
        float* o = uv + (size_t)n * 8;
        #pragma unroll
        for (int h = 0; h < 4; h++) {
            float inv = 1.f / (den[h] + 1e-16f);
            float u = sx[h] * inv, v = sy[h] * inv;
            o[h] = u; o[4 + h] = v;
            st[h] = u; st[4 + h] = v;
            st[8 + h] = u * u; st[12 + h] = v * v; st[16 + h] = u * v;
        }
    }
    #pragma unroll
    for (int i = 0; i < 20; i++)
        for (int o = 32; o; o >>= 1) st[i] += __shfl_down(st[i], o);
    if (lane == 0)
        #pragma unroll
        for (int i = 0; i < 20; i++) sred[wid][i] = st[i];
    __syncthreads();
    if (tid < 20)
        atomicAdd(&stats[tid], sred[0][tid] + sred[1][tid] + sred[2][tid] + sred[3][tid]);
}

// ---------- Layer 2 GEMM via MFMA; 512 threads / 128 rows per block ----------
__global__ __launch_bounds__(512) void k_gemm2(
        const float* __restrict__ uv, const float* __restrict__ stats,
        const float* __restrict__ W1, const float* __restrict__ b1,
        const float* __restrict__ gamma, const float* __restrict__ beta,
        const _Float16* __restrict__ w2t,
        const float* __restrict__ asw, const float* __restrict__ adw,
        _Float16* __restrict__ g2h, float* __restrict__ as2,
        float* __restrict__ ad2, int N) {
    __shared__ _Float16 bs[128][136];
    __shared__ float abcs[768];
    int tid = threadIdx.x, wid = tid >> 6, l = tid & 63;
    int kg = l >> 4, ln = l & 15;
    int n0w = blockIdx.x * 128 + wid * 16;

    if (tid < 256) {
        int j = tid, h = j >> 6;
        float w0 = W1[j], w1 = W1[256 + j], b = b1[j];
        float Su = stats[h], Sv = stats[4 + h], Suu = stats[8 + h],
              Svv = stats[12 + h], Suv = stats[16 + h];
        float fN = (float)N;
        float lin = fmaf(w0, Su, w1 * Sv);
        float mean = lin / fN + b;
        float sq = w0 * w0 * Suu + w1 * w1 * Svv + 2.f * w0 * w1 * Suv + 2.f * b * lin + fN * b * b;
        float var = sq / fN - mean * mean;
        float sc = rsqrtf(var + BN_EPS) * gamma[j];
        float sh = beta[j] - mean * sc;
        abcs[j] = sc * w0;
        abcs[256 + j] = sc * w1;
        abcs[512 + j] = fmaf(sc, b, sh);
    }

    int arow = n0w + ln;
    float uvr[8];
    if (arow < N) {
        const float4* p = (const float4*)(uv + (size_t)arow * 8);
        float4 t0 = p[0], t1 = p[1];
        uvr[0] = t0.x; uvr[1] = t0.y; uvr[2] = t0.z; uvr[3] = t0.w;
        uvr[4] = t1.x; uvr[5] = t1.y; uvr[6] = t1.z; uvr[7] = t1.w;
    } else {
        #pragma unroll
        for (int i = 0; i < 8; i++) uvr[i] = 0.f;
    }

    f32x4 acc[8];
    #pragma unroll
    for (int ct = 0; ct < 8; ct++) acc[ct] = (f32x4){0.f, 0.f, 0.f, 0.f};

    int sc_ = tid >> 2, q = tid & 3;
    for (int s = 0; s < 2; s++) {
        #pragma unroll
        for (int j = 0; j < 4; j++) {
            *(half8*)&bs[sc_][q * 32 + j * 8] =
                *(const half8*)&w2t[(size_t)sc_ * 256 + s * 128 + q * 32 + j * 8];
        }
        __syncthreads();
        #pragma unroll
        for (int kt4 = 0; kt4 < 4; kt4++) {
            int kt = s * 4 + kt4;
            int h = kt >> 1;
            float u = uvr[h], v = uvr[4 + h];
            int kb = kt * 32 + kg * 8;
            float4 A0a = *(const float4*)&abcs[kb],       A0b = *(const float4*)&abcs[kb + 4];
            float4 A1a = *(const float4*)&abcs[256 + kb], A1b = *(const float4*)&abcs[256 + kb + 4];
            float4 A2a = *(const float4*)&abcs[512 + kb], A2b = *(const float4*)&abcs[512 + kb + 4];
            half8 af;
            float y;
            y = fmaf(A0a.x, u, fmaf(A1a.x, v, A2a.x)); af[0] = (_Float16)(y > 0.f ? y : __expf(y) - 1.f);
            y = fmaf(A0a.y, u, fmaf(A1a.y, v, A2a.y)); af[1] = (_Float16)(y > 0.f ? y : __expf(y) - 1.f);
            y = fmaf(A0a.z, u, fmaf(A1a.z, v, A2a.z)); af[2] = (_Float16)(y > 0.f ? y : __expf(y) - 1.f);
            y = fmaf(A0a.w, u, fmaf(A1a.w, v, A2a.w)); af[3] = (_Float16)(y > 0.f ? y : __expf(y) - 1.f);
            y = fmaf(A0b.x, u, fmaf(A1b.x, v, A2b.x)); af[4] = (_Float16)(y > 0.f ? y : __expf(y) - 1.f);
            y = fmaf(A0b.y, u, fmaf(A1b.y, v, A2b.y)); af[5] = (_Float16)(y > 0.f ? y : __expf(y) - 1.f);
            y = fmaf(A0b.z, u, fmaf(A1b.z, v, A2b.z)); af[6] = (_Float16)(y > 0.f ? y : __expf(y) - 1.f);
            y = fmaf(A0b.w, u, fmaf(A1b.w, v, A2b.w)); af[7] = (_Float16)(y > 0.f ? y : __expf(y) - 1.f);
            int klo = kt4 * 32 + kg * 8;
            #pragma unroll
            for (int ct = 0; ct < 8; ct++) {
                half8 bf = *(const half8*)&bs[ct * 16 + ln][klo];
                acc[ct] = __builtin_amdgcn_mfma_f32_16x16x32_f16(af, bf, acc[ct], 0, 0, 0);
            }
        }
        __syncthreads();
    }

    _Float16 (*tbuf)[16][136] = (_Float16 (*)[16][136])&bs[0][0];
    #pragma unroll
    for (int ct = 0; ct < 8; ct++)
        #pragma unroll
        for (int r = 0; r < 4; r++)
            tbuf[wid][kg * 4 + r][ct * 16 + ln] = (_Float16)acc[ct][r];
    __syncthreads();

    int rr = l >> 2, cq = l & 3;
    int node = n0w + rr;
    half8 hv[4];
    #pragma unroll
    for (int j = 0; j < 4; j++) hv[j] = *(const half8*)&tbuf[wid][rr][cq * 32 + j * 8];
    float ps = 0.f, pd = 0.f;
    #pragma unroll
    for (int j = 0; j < 4; j++) {
        int cb = cq * 32 + j * 8;
        float4 s0 = *(const float4*)&asw[cb], s1 = *(const float4*)&asw[cb + 4];
        float4 d0 = *(const float4*)&adw[cb], d1 = *(const float4*)&adw[cb + 4];
        ps = fmaf((float)hv[j][0], s0.x, ps); pd = fmaf((float)hv[j][0], d0.x, pd);
        ps = fmaf((float)hv[j][1], s0.y, ps); pd = fmaf((float)hv[j][1], d0.y, pd);
        ps = fmaf((float)hv[j][2], s0.z, ps); pd = fmaf((float)hv[j][2], d0.z, pd);
        ps = fmaf((float)hv[j][3], s0.w, ps); pd = fmaf((float)hv[j][3], d0.w, pd);
        ps = fmaf((float)hv[j][4], s1.x, ps); pd = fmaf((float)hv[j][4], d1.x, pd);
        ps = fmaf((float)hv[j][5], s1.y, ps); pd = fmaf((float)hv[j][5], d1.y, pd);
        ps = fmaf((float)hv[j][6], s1.z, ps); pd = fmaf((float)hv[j][6], d1.z, pd);
        ps = fmaf((float)hv[j][7], s1.w, ps); pd = fmaf((float)hv[j][7], d1.w, pd);
    }
    ps += __shfl_xor(ps, 1); ps += __shfl_xor(ps, 2);
    pd += __shfl_xor(pd, 1); pd += __shfl_xor(pd, 2);
    if (node < N) {
        #pragma unroll
        for (int j = 0; j < 4; j++)
            *(half8*)&g2h[(size_t)node * 128 + cq * 32 + j * 8] = hv[j];
        if (cq == 0) { as2[node] = ps; ad2[node] = pd; }
    }
}

// ---------- Layer 2 aggregation: TWO nodes per wave (half-wave each),
//            32 lanes x 8B gathers, 4-edge unrolled ----------
__global__ void k_agg2(const int* __restrict__ rp, const int* __restrict__ esrc,
                       const float* __restrict__ as2, const float* __restrict__ ad2,
                       const _Float16* __restrict__ g2h, const float* __restrict__ b2,
                       _Float16* __restrict__ out2h, int N) {
    int wid = threadIdx.x >> 6, lane = threadIdx.x & 63;
    int half = lane >> 5, sl32 = lane & 31;
    int n = blockIdx.x * 8 + wid * 2 + half;
    if (n >= N) return;
    int beg = rp[n], end = rp[n + 1];
    float ad = ad2[n];
    int hbase = half << 5;  // shfl source base for this half-wave
    float a0 = 0.f, a1 = 0.f, a2 = 0.f, a3 = 0.f, den = 0.f;
    for (int t0 = beg; t0 < end; t0 += 32) {
        int k = t0 + sl32;
        int sl = 0; float wl = 0.f;
        if (k < end) {
            sl = esrc[k];
            float e = as2[sl] + ad;
            e = e > 0.f ? e : NEG_SLOPE * e;
            wl = __expf(e);
        }
        int nt = min(32, end - t0);
        int k2 = 0;
        for (; k2 + 3 < nt; k2 += 4) {
            float w0 = __shfl(wl, hbase + k2),     w1 = __shfl(wl, hbase + k2 + 1);
            float w2 = __shfl(wl, hbase + k2 + 2), w3 = __shfl(wl, hbase + k2 + 3);
            int   s0 = __shfl(sl, hbase + k2),     s1 = __shfl(sl, hbase + k2 + 1);
            int   s2 = __shfl(sl, hbase + k2 + 2), s3 = __shfl(sl, hbase + k2 + 3);
            half4v g0 = ((const half4v*)g2h)[(size_t)s0 * 32 + sl32];
            half4v g1 = ((const half4v*)g2h)[(size_t)s1 * 32 + sl32];
            half4v g2 = ((const half4v*)g2h)[(size_t)s2 * 32 + sl32];
            half4v g3 = ((const half4v*)g2h)[(size_t)s3 * 32 + sl32];
            den += (w0 + w1) + (w2 + w3);
            a0 = fmaf(w0, (float)g0[0], a0); a1 = fmaf(w0, (float)g0[1], a1);
            a2 = fmaf(w0, (float)g0[2], a2); a3 = fmaf(w0, (float)g0[3], a3);
            a0 = fmaf(w1, (float)g1[0], a0); a1 = fmaf(w1, (float)g1[1], a1);
            a2 = fmaf(w1, (float)g1[2], a2); a3 = fmaf(w1, (float)g1[3], a3);
            a0 = fmaf(w2, (float)g2[0], a0); a1 = fmaf(w2, (float)g2[1], a1);
            a2 = fmaf(w2, (float)g2[2], a2); a3 = fmaf(w2, (float)g2[3], a3);
            a0 = fmaf(w3, (float)g3[0], a0); a1 = fmaf(w3, (float)g3[1], a1);
            a2 = fmaf(w3, (float)g3[2], a2); a3 = fmaf(w3, (float)g3[3], a3);
        }
        for (; k2 < nt; k2++) {
            float w = __shfl(wl, hbase + k2);
            int s = __shfl(sl, hbase + k2);
            half4v gv = ((const half4v*)g2h)[(size_t)s * 32 + sl32];
            den += w;
            a0 = fmaf(w, (float)gv[0], a0); a1 = fmaf(w, (float)gv[1], a1);
            a2 = fmaf(w, (float)gv[2], a2); a3 = fmaf(w, (float)gv[3], a3);
        }
    }
    float inv = 1.f / (den + 1e-16f);
    float4 bv = ((const float4*)b2)[sl32];
    half4v ov;
    ov[0] = (_Float16)(a0 * inv + bv.x);
    ov[1] = (_Float16)(a1 * inv + bv.y);
    ov[2] = (_Float16)(a2 * inv + bv.z);
    ov[3] = (_Float16)(a3 * inv + bv.w);
    ((half4v*)out2h)[(size_t)n * 32 + sl32] = ov;
}

// ---------- BN2 stats: vectorized half8 loads ----------
__global__ void k_bnstats(const _Float16* __restrict__ v, int N,
                          float* __restrict__ sum, float* __restrict__ sq) {
    __shared__ float wred[4][16][16];
    int t = threadIdx.x;
    int rr = t >> 4, cg = t & 15;
    int rows = (N + gridDim.x - 1) / gridDim.x;
    int r0 = blockIdx.x * rows, r1 = min(N, r0 + rows);
    float s[8], q[8];
    #pragma unroll
    for (int i = 0; i < 8; i++) { s[i] = 0.f; q[i] = 0.f; }
    for (int r = r0 + rr; r < r1; r += 16) {
        half8 hv = *(const half8*)&v[(size_t)r * 128 + cg * 8];
        #pragma unroll
        for (int i = 0; i < 8; i++) {
            float xx = (float)hv[i];
            s[i] += xx; q[i] = fmaf(xx, xx, q[i]);
        }
    }
    #pragma unroll
    for (int i = 0; i < 8; i++) {
        s[i] += __shfl_xor(s[i], 16); s[i] += __shfl_xor(s[i], 32);
        q[i] += __shfl_xor(q[i], 16); q[i] += __shfl_xor(q[i], 32);
    }
    int wave = t >> 6, lane = t & 63;
    if (lane < 16) {
        #pragma unroll
        for (int i = 0; i < 8; i++) {
            wred[wave][lane][i] = s[i];
            wred[wave][lane][8 + i] = q[i];
        }
    }
    __syncthreads();
    {
        int cg2 = t >> 4, e = t & 15;
        float tot = wred[0][cg2][e] + wred[1][cg2][e] + wred[2][cg2][e] + wred[3][cg2][e];
        if (e < 8) atomicAdd(&sum[cg2 * 8 + e], tot);
        else       atomicAdd(&sq[cg2 * 8 + e - 8], tot);
    }
}

// ---------- pooling: one block per (graph, quarter); vectorized ----------
__global__ void k_poolg2(const _Float16* __restrict__ v, const int* __restrict__ gb,
                         const float* __restrict__ bnsum, const float* __restrict__ bnsq,
                         const float* __restrict__ gamma, const float* __restrict__ beta,
                         float* __restrict__ out, int N) {
    __shared__ float wred[4][16][8];
    int t = threadIdx.x;
    int g = blockIdx.x >> 2, qtr = blockIdx.x & 3;
    int rr = t >> 4, cg = t & 15;
    int gs = gb[g], ge = gb[g + 1];
    int len = ge - gs;
    int q0 = gs + (len * qtr) / 4, q1 = gs + (len * (qtr + 1)) / 4;
    float sc[8], sh[8];
    #pragma unroll
    for (int i = 0; i < 8; i++) {
        int j = cg * 8 + i;
        float mu = bnsum[j] / N;
        float var = bnsq[j] / N - mu * mu;
        sc[i] = rsqrtf(var + BN_EPS) * gamma[j];
        sh[i] = beta[j] - mu * sc[i];
    }
    float acc[8];
    #pragma unroll
    for (int i = 0; i < 8; i++) acc[i] = 0.f;
    for (int r = q0 + rr; r < q1; r += 16) {
        half8 hv = *(const half8*)&v[(size_t)r * 128 + cg * 8];
        #pragma unroll
        for (int i = 0; i < 8; i++) {
            float y = fmaf((float)hv[i], sc[i], sh[i]);
            acc[i] += y > 0.f ? y : (__expf(y) - 1.0f);
        }
    }
    #pragma unroll
    for (int i = 0; i < 8; i++) {
        acc[i] += __shfl_xor(acc[i], 16);
        acc[i] += __shfl_xor(acc[i], 32);
    }
    int wave = t >> 6, lane = t & 63;
    if (lane < 16) {
        #pragma unroll
        for (int i = 0; i < 8; i++) wred[wave][lane][i] = acc[i];
    }
    __syncthreads();
    if (t < 128) {
        int cg2 = t >> 3, e = t & 7;
        float tot = wred[0][cg2][e] + wred[1][cg2][e] + wred[2][cg2][e] + wred[3][cg2][e];
        float invc = 1.f / fmaxf((float)len, 1.0f);
        atomicAdd(&out[(size_t)g * 128 + cg2 * 8 + e], tot * invc);
    }
}

extern "C" void kernel_launch(void* const* d_in, const int* in_sizes, int n_in,
                              void* d_out, int out_size, void* d_ws, size_t ws_size,
                              hipStream_t stream) {
    const float* x     = (const float*)d_in[0];
    const int*   ei    = (const int*)d_in[1];
    const int*   batch = (const int*)d_in[2];
    const float* W1    = (const float*)d_in[4];
    const float* asw1  = (const float*)d_in[5];
    const float* adw1  = (const float*)d_in[6];
    const float* b1    = (const float*)d_in[7];
    const float* gamma1= (const float*)d_in[8];
    const float* beta1 = (const float*)d_in[9];
    const float* W2    = (const float*)d_in[10];
    const float* asw2  = (const float*)d_in[11];
    const float* adw2  = (const float*)d_in[12];
    const float* b2    = (const float*)d_in[13];
    const float* gamma2= (const float*)d_in[14];
    const float* beta2 = (const float*)d_in[15];
    float* out = (float*)d_out;

    const int N  = in_sizes[2];
    const int E  = in_sizes[1] / 2;
    const int E2 = E + N;
    const int G  = out_size / 128;

    char* ws = (char*)d_ws;
    size_t off = 0;
    auto A = [&](size_t bytes) { size_t o = off; off += (bytes + 255) & ~(size_t)255; return o; };
    _Float16* g2h  = (_Float16*)(ws + A((size_t)N * 128 * 2));
    _Float16* w2t  = (_Float16*)(ws + A((size_t)128 * 256 * 2));
    _Float16* out2h= (_Float16*)(ws + A((size_t)N * 128 * 2));
    float* uv    = (float*)(ws + A((size_t)N * 8 * 4));
    float* as2   = (float*)(ws + A((size_t)N * 4));
    float* ad2   = (float*)(ws + A((size_t)N * 4));
    float* coef  = (float*)(ws + A(16 * 4));
    int*   gb    = (int*)(ws + A((size_t)(G + 1) * 4));
    int*   rp    = (int*)(ws + A((size_t)(N + 1) * 4));
    int*   esrc  = (int*)(ws + A((size_t)E2 * 4));
    int*   bsums = (int*)(ws + A((size_t)((N + 1023) / 1024) * 4));
    size_t zbytes = ((size_t)N + 20 + 256 + 256) * 4;
    size_t zoff = A(zbytes);
    int*   cnt   = (int*)(ws + zoff);
    float* stats = (float*)(cnt + N);
    float* bnsum = stats + 20;
    float* bnsq  = bnsum + 256;

    const int nb = (N + 1023) / 1024;

    // 1: zero scratch AND the full output buffer
    int n4 = (int)((zbytes + 15) / 16);
    int m4 = (out_size + 3) / 4;
    k_zero<<<(n4 + m4 + 255) / 256, 256, 0, stream>>>((uint4*)(ws + zoff), n4,
                                                      (uint4*)out, m4);

    // 2: setup
    int degBlocks = (E2 + 255) / 256;
    k_setup<<<34 + degBlocks, 256, 0, stream>>>(W1, asw1, adw1, coef, W2, w2t,
                                                batch, N, G, gb, ei, E, E2, cnt);

    // 3-4: hierarchical scan -> rp
    k_scan1<<<nb, 1024, 0, stream>>>(cnt, rp, bsums, N);
    k_scan2f<<<nb, 1024, 0, stream>>>(rp, bsums, N, E2, nb);

    // 5: scatter
    k_scatter<<<degBlocks, 256, 0, stream>>>(ei, E, E2, rp, cnt, esrc);

    // 6: layer-1 rank-2 aggregation + BN1 stats
    k_agg1r<<<(N + 255) / 256, 256, 0, stream>>>(rp, esrc, x, coef, uv, stats, N);

    // 7: layer-2 GEMM via MFMA
    k_gemm2<<<(N + 127) / 128, 512, 0, stream>>>(uv, stats, W1, b1, gamma1, beta1,
                                                 w2t, asw2, adw2, g2h, as2, ad2, N);

    // 8: layer-2 aggregation (2 nodes/wave, 8B gathers, 4-edge unrolled)
    k_agg2<<<(N + 7) / 8, 256, 0, stream>>>(rp, esrc, as2, ad2, g2h, b2, out2h, N);

    // 9: BN2 stats
    k_bnstats<<<512, 256, 0, stream>>>(out2h, N, bnsum, bnsq);

    // 10: pooling
    k_poolg2<<<G * 4, 256, 0, stream>>>(out2h, gb, bnsum, bnsq, gamma2, beta2, out, N);
}